// Round 8
// baseline (190.214 us; speedup 1.0000x reference)
//
#include <hip/hip_runtime.h>
#include <hip/hip_bf16.h>

typedef unsigned short u16;
typedef unsigned int u32;
typedef __attribute__((ext_vector_type(8))) short bf16x8;   // 8 bf16 = 4 VGPRs (MFMA A/B frag)
typedef __attribute__((ext_vector_type(4))) float f32x4;    // MFMA C/D frag

#define BB 4
#define NN 2048
#define DD 256
#define HH 8
#define LAMBDA 0.17677669529f   // 1/sqrt(32), natural-log units (__expf supplies log2e)

__device__ inline u16 bfu(float f) {
  __hip_bfloat16 h = __float2bfloat16(f);
  return *reinterpret_cast<u16*>(&h);
}
__device__ inline bf16x8 asfrag(uint4 v) { return __builtin_bit_cast(bf16x8, v); }

// ---------------- merged prep: x(permuted)+xb, mask->u8, weights ----------------
// xp[row][c*16+j] = x[row][16j+c]  (fragment-friendly layout for the tail kernel:
// lane c's 16 columns {16j+c} become 64 contiguous bytes)
__global__ __launch_bounds__(256) void prep_kernel(
    const float* __restrict__ qdt, const float* __restrict__ boxes,
    const int* __restrict__ mask,
    const float* __restrict__ Wq, const float* __restrict__ Wk, const float* __restrict__ Wv,
    const float* __restrict__ Wo, const float* __restrict__ W1, const float* __restrict__ W2,
    const float* __restrict__ bq, const float* __restrict__ bk, const float* __restrict__ bv,
    float* __restrict__ xp, u16* __restrict__ xb, unsigned char* __restrict__ m8,
    u16* __restrict__ wqkvT, u16* __restrict__ woT, u16* __restrict__ w1T, u16* __restrict__ w2T,
    float* __restrict__ bqkv) {
  const int bid = blockIdx.x, t = threadIdx.x;
  if (bid < 2048) {                       // x = qdt + boxes (permuted fp32 + linear bf16)
    int i = bid * 256 + t;
    int row = i >> 6, q = i & 63;
    float4 a = ((const float4*)qdt)[i];
    float4 b = ((const float4*)boxes)[i];
    float4 v = make_float4(a.x + b.x, a.y + b.y, a.z + b.z, a.w + b.w);
    ((ushort4*)xb)[i] = make_ushort4(bfu(v.x), bfu(v.y), bfu(v.z), bfu(v.w));
    float* xr = xp + (size_t)row * 256;
    xr[((4*q+0) & 15) * 16 + ((4*q+0) >> 4)] = v.x;
    xr[((4*q+1) & 15) * 16 + ((4*q+1) >> 4)] = v.y;
    xr[((4*q+2) & 15) * 16 + ((4*q+2) >> 4)] = v.z;
    xr[((4*q+3) & 15) * 16 + ((4*q+3) >> 4)] = v.w;
  } else if (bid < 6144) {                // mask int -> u8 0/1
    int i = (bid - 2048) * 256 + t;
    int4 m = ((const int4*)mask)[i];
    ((uchar4*)m8)[i] = make_uchar4((unsigned char)m.x, (unsigned char)m.y,
                                   (unsigned char)m.z, (unsigned char)m.w);
  } else {                                // weight transposes + qkv bias concat
    int i = (bid - 6144) * 256 + t;
    if (i < 196608) {
      int n = i >> 8, k = i & 255;
      const float* src = (n < 256) ? Wq : (n < 512 ? Wk : Wv);
      wqkvT[i] = bfu(src[k * 256 + (n & 255)]);
    } else if (i < 262144) {
      int j = i - 196608; int n = j >> 8, k = j & 255;
      woT[j] = bfu(Wo[k * 256 + n]);
    } else if (i < 327680) {
      int j = i - 262144; int n = j >> 8, k = j & 255;
      w1T[j] = bfu(W1[k * 256 + n]);
    } else if (i < 393216) {
      int j = i - 327680; int n = j >> 8, k = j & 255;
      w2T[j] = bfu(W2[k * 256 + n]);
    } else if (i < 393984) {
      int n = i - 393216;
      bqkv[n] = (n < 256) ? bq[n] : (n < 512 ? bk[n - 256] : bv[n - 512]);
    }
  }
}

// ============ shared GEMM body: C = A[M,256] @ Bt[N,256]^T, 64x64 tile ============
#define GEMM_BODY()                                                              \
  __shared__ u16 At[64][264];                                                    \
  __shared__ u16 Bs[64][264];                                                    \
  const int m0 = blockIdx.x * 64;                                                \
  const int n0 = blockIdx.y * 64;                                                \
  const int t = threadIdx.x;                                                     \
  {                                                                              \
    const int row = t >> 2, cb = (t & 3) * 64;                                   \
    const u16* ga = A  + (size_t)(m0 + row) * 256 + cb;                          \
    const u16* gb = Bt + (size_t)(n0 + row) * 256 + cb;                          \
    _Pragma("unroll")                                                            \
    for (int i = 0; i < 8; ++i) {                                                \
      *(int4*)&At[row][cb + i * 8] = *(const int4*)(ga + i * 8);                 \
      *(int4*)&Bs[row][cb + i * 8] = *(const int4*)(gb + i * 8);                 \
    }                                                                            \
  }                                                                              \
  __syncthreads();                                                               \
  const int w = t >> 6, l = t & 63, g = l >> 4, c = l & 15;                      \
  f32x4 acc[4] = {};                                                             \
  _Pragma("unroll")                                                              \
  for (int kk = 0; kk < 256; kk += 32) {                                         \
    bf16x8 af = *(const bf16x8*)&At[w * 16 + c][kk + g * 8];                     \
    _Pragma("unroll")                                                            \
    for (int j = 0; j < 4; ++j) {                                                \
      bf16x8 bfr = *(const bf16x8*)&Bs[j * 16 + c][kk + g * 8];                  \
      acc[j] = __builtin_amdgcn_mfma_f32_16x16x32_bf16(af, bfr, acc[j], 0, 0, 0);\
    }                                                                            \
  }

// QKV (q,k part): q scaled by LAMBDA -> [8192][256]; k -> [B][H][2048][32]
__global__ __launch_bounds__(256) void gemm_qk_kernel(
    const u16* __restrict__ A, const u16* __restrict__ Bt, const float* __restrict__ bias,
    u16* __restrict__ qout, u16* __restrict__ kout) {
  GEMM_BODY()
  if (n0 < 256) {
#pragma unroll
    for (int j = 0; j < 4; ++j)
#pragma unroll
      for (int r = 0; r < 4; ++r) {
        int m = m0 + w * 16 + g * 4 + r, n = n0 + j * 16 + c;
        qout[(size_t)m * 256 + n] = bfu((acc[j][r] + bias[n]) * LAMBDA);
      }
  } else {
#pragma unroll
    for (int j = 0; j < 4; ++j)
#pragma unroll
      for (int r = 0; r < 4; ++r) {
        int m = m0 + w * 16 + g * 4 + r, n = n0 + j * 16 + c;
        int ch = n - 256;
        kout[(size_t)((m >> 11) * 8 + (ch >> 5)) * 65536 + (size_t)(m & 2047) * 32 + (ch & 31)]
            = bfu(acc[j][r] + bias[n]);
      }
  }
}

// V^T: A = WvT[256][256], Bt = xb[8192][256] -> vT[256][8192], bias by m(channel)
__global__ __launch_bounds__(256) void gemm_vt_kernel(
    const u16* __restrict__ A, const u16* __restrict__ Bt, const float* __restrict__ bias,
    u16* __restrict__ vtout) {
  GEMM_BODY()
#pragma unroll
  for (int j = 0; j < 4; ++j)
#pragma unroll
    for (int r = 0; r < 4; ++r) {
      int m = m0 + w * 16 + g * 4 + r;   // channel
      int n = n0 + j * 16 + c;           // token
      vtout[(size_t)m * 8192 + n] = bfu(acc[j][r] + bias[m]);
    }
}

// ---------------- fused sigmoid-gated attention (round-6 PASSING build) ----------------
__global__ __launch_bounds__(256) void attn_kernel(
    const u16* __restrict__ qb,            // [8192][256] bf16, LAMBDA-scaled
    const u16* __restrict__ kb,            // [B][H][2048][32] bf16
    const u16* __restrict__ vtb,           // [256][8192] bf16 (V^T)
    const unsigned char* __restrict__ m8,  // [2048][2048] 0/1
    u16* __restrict__ ob) {                // [8192][256] bf16
  __shared__ u32 Klds[2][64][20];          // 16 data u32 + 4 pad (row 80 B)
  __shared__ u32 Vlds[2][32][36];          // 32 data u32 + 4 pad (row 144 B)
  __shared__ unsigned char Mlds[2][64][64];// mask tile, byte-rotated rows
  __shared__ u32 Plds[4][16][36];          // 32 data u32 + 4 pad, per-wave

  const int bid = blockIdx.x;
  const int qt = bid & 31, h = (bid >> 5) & 7, b = bid >> 8;
  const int q0 = qt * 64;
  const int t = threadIdx.x, w = t >> 6, l = t & 63, g = l >> 4, c = l & 15;

  const bf16x8 qf = asfrag(*(const uint4*)(qb + (size_t)(b * NN + q0 + 16 * w + c) * 256 + h * 32 + 8 * g));
  f32x4 oacc[2] = {};

  const int srowK = t >> 2, ssegK = t & 3;
  const int srowV = t >> 3, ssegV = t & 7;
  const u16* kg = kb + (size_t)(b * 8 + h) * 65536 + srowK * 32 + ssegK * 8;
  const u16* vg = vtb + (size_t)(h * 32 + srowV) * 8192 + (size_t)b * NN + ssegV * 8;
  const unsigned char* mg = m8 + (size_t)(q0 + srowK) * NN + ssegK * 16;

  const int mb0 = (16 * ssegK + 8 * (srowK & 7)) & 63;
  const int mb1 = (mb0 + 8) & 63;

  uint4 krg = *(const uint4*)kg;
  uint4 vrg = *(const uint4*)vg;
  uint4 mrg = *(const uint4*)mg;
  *(uint4*)&Klds[0][srowK][ssegK * 4] = krg;
  *(uint4*)&Vlds[0][srowV][ssegV * 4] = vrg;
  *(uint2*)&Mlds[0][srowK][mb0] = make_uint2(mrg.x, mrg.y);
  *(uint2*)&Mlds[0][srowK][mb1] = make_uint2(mrg.z, mrg.w);
  __syncthreads();

  const f32x4 zf = {0.f, 0.f, 0.f, 0.f};
  u32* Pw = &Plds[w][0][0];

  for (int it = 0; it < 32; ++it) {
    const int cur = it & 1;
    if (it < 31) {
      const int kt = (it + 1) * 64;
      krg = *(const uint4*)(kg + (size_t)kt * 32);
      vrg = *(const uint4*)(vg + kt);
      mrg = *(const uint4*)(mg + kt);
    }
#pragma unroll
    for (int tt = 0; tt < 4; ++tt) {
      bf16x8 kf = asfrag(*(const uint4*)&Klds[cur][16 * tt + c][4 * g]);
      f32x4 s = __builtin_amdgcn_mfma_f32_16x16x32_bf16(kf, qf, zf, 0, 0, 0);
      u32 mdw = *(const u32*)&Mlds[cur][16 * w + c][(16 * tt + 4 * g + 8 * (c & 7)) & 63];
      float mf0 = (float)(mdw & 0xffu);
      float mf1 = (float)((mdw >> 8) & 0xffu);
      float mf2 = (float)((mdw >> 16) & 0xffu);
      float mf3 = (float)(mdw >> 24);
      float p0 = mf0 * __builtin_amdgcn_rcpf(1.f + __expf(-s[0]));
      float p1 = mf1 * __builtin_amdgcn_rcpf(1.f + __expf(-s[1]));
      float p2 = mf2 * __builtin_amdgcn_rcpf(1.f + __expf(-s[2]));
      float p3 = mf3 * __builtin_amdgcn_rcpf(1.f + __expf(-s[3]));
      u32 w0, w1;
      asm("v_cvt_pk_bf16_f32 %0, %1, %2" : "=v"(w0) : "v"(p0), "v"(p1));
      asm("v_cvt_pk_bf16_f32 %0, %1, %2" : "=v"(w1) : "v"(p2), "v"(p3));
      *(uint2*)&Pw[c * 36 + 8 * tt + 2 * g] = make_uint2(w0, w1);
    }
    asm volatile("s_waitcnt lgkmcnt(0)" ::: "memory");
    __builtin_amdgcn_sched_barrier(0);
#pragma unroll
    for (int kk = 0; kk < 2; ++kk) {
      bf16x8 pf = asfrag(*(const uint4*)&Pw[c * 36 + 16 * kk + 4 * g]);
#pragma unroll
      for (int d0 = 0; d0 < 2; ++d0) {
        bf16x8 vf = asfrag(*(const uint4*)&Vlds[cur][16 * d0 + c][16 * kk + 4 * g]);
        oacc[d0] = __builtin_amdgcn_mfma_f32_16x16x32_bf16(pf, vf, oacc[d0], 0, 0, 0);
      }
    }
    if (it < 31) {
      *(uint4*)&Klds[cur ^ 1][srowK][ssegK * 4] = krg;
      *(uint4*)&Vlds[cur ^ 1][srowV][ssegV * 4] = vrg;
      *(uint2*)&Mlds[cur ^ 1][srowK][mb0] = make_uint2(mrg.x, mrg.y);
      *(uint2*)&Mlds[cur ^ 1][srowK][mb1] = make_uint2(mrg.z, mrg.w);
    }
    __syncthreads();
  }

  const size_t obase = (size_t)(b * NN + q0 + 16 * w) * 256 + h * 32;
#pragma unroll
  for (int d0 = 0; d0 < 2; ++d0)
#pragma unroll
    for (int r = 0; r < 4; ++r)
      ob[obase + (size_t)(4 * g + r) * 256 + 16 * d0 + c] = bfu(oacc[d0][r]);
}

// ---------------- fused tail: Wo+res -> LN1 -> FF1+relu -> FF2+res -> LN2 ----------------
// 128 blocks x 4 waves; wave = 16 rows x full 256 cols -> ALL LDS traffic is
// wave-local (A-frag rows 16w+c, transposes write rows 16w+4g+r) => NO barriers,
// only rule-18 fences. B-operands (woT/w1T/w2T) read per-fragment from L2.
// t1 (LN1 output) stays in 64 f32 regs for the FF2 residual.
__global__ __launch_bounds__(256, 1) void tail_kernel(
    const u16* __restrict__ obuf, const u16* __restrict__ woT,
    const u16* __restrict__ w1T, const u16* __restrict__ w2T,
    const float* __restrict__ xp,          // [8192][256] f32, permuted [row][c*16+j]
    const float* __restrict__ bo, const float* __restrict__ b1, const float* __restrict__ b2,
    const float* __restrict__ g1, const float* __restrict__ be1,
    const float* __restrict__ g2, const float* __restrict__ be2,
    float* __restrict__ out) {
  __shared__ u16 At[4][16][264];           // per-wave 16 rows x 264 (pad) bf16
  const int t = threadIdx.x, w = t >> 6, l = t & 63, g = l >> 4, c = l & 15;
  const int m0 = blockIdx.x * 64 + w * 16; // this wave's 16 rows
  u16 (*A)[264] = At[w];
  const f32x4 zf4 = {0.f, 0.f, 0.f, 0.f};

  // ---- stage obuf rows m0..m0+15 (wave-local, coalesced) ----
  {
    const int rr = l >> 5, ss = l & 31;    // 2 rows x 32 segs of 16B per iter
#pragma unroll
    for (int i = 0; i < 8; ++i) {
      uint4 v = *(const uint4*)(obuf + (size_t)(m0 + 2 * i + rr) * 256 + ss * 8);
      *(uint4*)&A[2 * i + rr][ss * 8] = v;
    }
  }
  asm volatile("s_waitcnt lgkmcnt(0)" ::: "memory");
  __builtin_amdgcn_sched_barrier(0);

  f32x4 acc[16], t1[16];

  // ---- GEMM1: obuf @ Wo ----
#pragma unroll
  for (int j = 0; j < 16; ++j) acc[j] = zf4;
#pragma unroll
  for (int kk = 0; kk < 256; kk += 32) {
    bf16x8 af = *(const bf16x8*)&A[c][kk + 8 * g];
#pragma unroll
    for (int j = 0; j < 16; ++j) {
      bf16x8 bfr = asfrag(*(const uint4*)(woT + (size_t)(16 * j + c) * 256 + kk + 8 * g));
      acc[j] = __builtin_amdgcn_mfma_f32_16x16x32_bf16(af, bfr, acc[j], 0, 0, 0);
    }
  }
  // ---- epilogue1: + bo + x, LN1 stats ----
  float bov[16];
#pragma unroll
  for (int j = 0; j < 16; ++j) bov[j] = bo[16 * j + c];
  float s1[4], s2[4];
#pragma unroll
  for (int r = 0; r < 4; ++r) {
    const float* xrow = xp + (size_t)(m0 + 4 * g + r) * 256 + c * 16;
    float4 xq0 = ((const float4*)xrow)[0], xq1 = ((const float4*)xrow)[1];
    float4 xq2 = ((const float4*)xrow)[2], xq3 = ((const float4*)xrow)[3];
    float xa[16] = {xq0.x, xq0.y, xq0.z, xq0.w, xq1.x, xq1.y, xq1.z, xq1.w,
                    xq2.x, xq2.y, xq2.z, xq2.w, xq3.x, xq3.y, xq3.z, xq3.w};
    float a1 = 0.f, a2 = 0.f;
#pragma unroll
    for (int j = 0; j < 16; ++j) {
      float z = acc[j][r] + bov[j] + xa[j];
      t1[j][r] = z;
      a1 += z; a2 += z * z;
    }
    s1[r] = a1; s2[r] = a2;
  }
#pragma unroll
  for (int r = 0; r < 4; ++r) {
#pragma unroll
    for (int off = 1; off < 16; off <<= 1) {
      s1[r] += __shfl_xor(s1[r], off);
      s2[r] += __shfl_xor(s2[r], off);
    }
  }
  float mean[4], inv[4];
#pragma unroll
  for (int r = 0; r < 4; ++r) {
    mean[r] = s1[r] * (1.f / 256.f);
    inv[r] = rsqrtf(s2[r] * (1.f / 256.f) - mean[r] * mean[r] + 1e-5f);
  }
  // normalize (t1 regs) + bf16 transpose -> LDS (wave-local rows 4g+r)
  asm volatile("" ::: "memory");
  __builtin_amdgcn_sched_barrier(0);
#pragma unroll
  for (int j = 0; j < 16; ++j) {
    const int n = 16 * j + c;
    const float gv = g1[n], bev = be1[n];
#pragma unroll
    for (int r = 0; r < 4; ++r) {
      float v = (t1[j][r] - mean[r]) * inv[r] * gv + bev;
      t1[j][r] = v;
      A[4 * g + r][n] = bfu(v);
    }
  }
  asm volatile("s_waitcnt lgkmcnt(0)" ::: "memory");
  __builtin_amdgcn_sched_barrier(0);

  // ---- GEMM2: t1 @ W1, relu ----
#pragma unroll
  for (int j = 0; j < 16; ++j) acc[j] = zf4;
#pragma unroll
  for (int kk = 0; kk < 256; kk += 32) {
    bf16x8 af = *(const bf16x8*)&A[c][kk + 8 * g];
#pragma unroll
    for (int j = 0; j < 16; ++j) {
      bf16x8 bfr = asfrag(*(const uint4*)(w1T + (size_t)(16 * j + c) * 256 + kk + 8 * g));
      acc[j] = __builtin_amdgcn_mfma_f32_16x16x32_bf16(af, bfr, acc[j], 0, 0, 0);
    }
  }
  asm volatile("" ::: "memory");       // WAR: stores below must not pass reads above
  __builtin_amdgcn_sched_barrier(0);
#pragma unroll
  for (int j = 0; j < 16; ++j) {
    const int n = 16 * j + c;
    const float bv = b1[n];
#pragma unroll
    for (int r = 0; r < 4; ++r) {
      float v = acc[j][r] + bv;
      A[4 * g + r][n] = bfu(v > 0.f ? v : 0.f);
    }
  }
  asm volatile("s_waitcnt lgkmcnt(0)" ::: "memory");
  __builtin_amdgcn_sched_barrier(0);

  // ---- GEMM3: h @ W2 ----
#pragma unroll
  for (int j = 0; j < 16; ++j) acc[j] = zf4;
#pragma unroll
  for (int kk = 0; kk < 256; kk += 32) {
    bf16x8 af = *(const bf16x8*)&A[c][kk + 8 * g];
#pragma unroll
    for (int j = 0; j < 16; ++j) {
      bf16x8 bfr = asfrag(*(const uint4*)(w2T + (size_t)(16 * j + c) * 256 + kk + 8 * g));
      acc[j] = __builtin_amdgcn_mfma_f32_16x16x32_bf16(af, bfr, acc[j], 0, 0, 0);
    }
  }
  // ---- epilogue3: + b2 + t1 residual, LN2 -> out ----
  float b2v[16];
#pragma unroll
  for (int j = 0; j < 16; ++j) b2v[j] = b2[16 * j + c];
#pragma unroll
  for (int r = 0; r < 4; ++r) {
    float a1 = 0.f, a2 = 0.f;
#pragma unroll
    for (int j = 0; j < 16; ++j) {
      float z = acc[j][r] + b2v[j] + t1[j][r];
      t1[j][r] = z;
      a1 += z; a2 += z * z;
    }
    s1[r] = a1; s2[r] = a2;
  }
#pragma unroll
  for (int r = 0; r < 4; ++r) {
#pragma unroll
    for (int off = 1; off < 16; off <<= 1) {
      s1[r] += __shfl_xor(s1[r], off);
      s2[r] += __shfl_xor(s2[r], off);
    }
    mean[r] = s1[r] * (1.f / 256.f);
    inv[r] = rsqrtf(s2[r] * (1.f / 256.f) - mean[r] * mean[r] + 1e-5f);
  }
#pragma unroll
  for (int j = 0; j < 16; ++j) {
    const int n = 16 * j + c;
    const float gv = g2[n], bev = be2[n];
#pragma unroll
    for (int r = 0; r < 4; ++r)
      out[(size_t)(m0 + 4 * g + r) * 256 + n] = (t1[j][r] - mean[r]) * inv[r] * gv + bev;
  }
}

extern "C" void kernel_launch(void* const* d_in, const int* in_sizes, int n_in,
                              void* d_out, int out_size, void* d_ws, size_t ws_size,
                              hipStream_t stream) {
  const float* qdt   = (const float*)d_in[0];
  const float* boxes = (const float*)d_in[1];
  const int*   mask  = (const int*)d_in[2];
  const float* Wq = (const float*)d_in[3];
  const float* bq = (const float*)d_in[4];
  const float* Wk = (const float*)d_in[5];
  const float* bk = (const float*)d_in[6];
  const float* Wv = (const float*)d_in[7];
  const float* bv = (const float*)d_in[8];
  const float* Wo = (const float*)d_in[9];
  const float* bo = (const float*)d_in[10];
  const float* W1 = (const float*)d_in[11];
  const float* b1 = (const float*)d_in[12];
  const float* W2 = (const float*)d_in[13];
  const float* b2 = (const float*)d_in[14];
  const float* g1  = (const float*)d_in[15];
  const float* be1 = (const float*)d_in[16];
  const float* g2  = (const float*)d_in[17];
  const float* be2 = (const float*)d_in[18];

  char* ws = (char*)d_ws;
  float* xp    = (float*)(ws + 0);          // [8192,256] f32 permuted residual
  u16*   xb    = (u16*)  (ws + 8388608);
  u16*   qbuf  = (u16*)  (ws + 12582912);   // q, LAMBDA-scaled
  u16*   kbuf  = (u16*)  (ws + 16777216);   // [B][H][2048][32]
  u16*   vtbuf = (u16*)  (ws + 20971520);   // [256][8192]
  u16*   obuf  = (u16*)  (ws + 25165824);
  u16*   wqkvT = (u16*)  (ws + 46137344);   // [768,256]
  u16*   woT   = (u16*)  (ws + 46530560);
  u16*   w1T   = (u16*)  (ws + 46661632);
  u16*   w2T   = (u16*)  (ws + 46792704);
  float* bqkv  = (float*)(ws + 46923776);
  unsigned char* m8 = (unsigned char*)(ws + 46926848);  // [2048,2048] u8

  // merged prep: xp/xb (2048 blk) + mask->m8 (4096 blk) + weights (1539 blk)
  prep_kernel<<<7683, 256, 0, stream>>>(qdt, boxes, mask, Wq, Wk, Wv, Wo, W1, W2,
                                        bq, bk, bv, xp, xb, m8,
                                        wqkvT, woT, w1T, w2T, bqkv);
  // Q (scaled) + K (relayout): [8192,256] x [256,512]
  gemm_qk_kernel<<<dim3(128, 8), 256, 0, stream>>>(xb, wqkvT, bqkv, qbuf, kbuf);
  // V^T: [256,256] x [256,8192]^T
  gemm_vt_kernel<<<dim3(4, 128), 256, 0, stream>>>(wqkvT + 512 * 256, xb, bqkv + 512, vtbuf);
  // attention
  attn_kernel<<<1024, 256, 0, stream>>>(qbuf, kbuf, vtbuf, m8, obuf);
  // fused tail: Wo+res -> LN1 -> FF1+relu -> FF2+res -> LN2 -> d_out
  tail_kernel<<<128, 256, 0, stream>>>(obuf, woT, w1T, w2T, xp,
                                       bo, b1, b2, g1, be1, g2, be2, (float*)d_out);
}

// Round 9
// 128.343 us; speedup vs baseline: 1.4821x; 1.4821x over previous
//
#include <hip/hip_runtime.h>
#include <hip/hip_bf16.h>

typedef unsigned short u16;
typedef unsigned int u32;
typedef __attribute__((ext_vector_type(8))) short bf16x8;   // 8 bf16 = 4 VGPRs (MFMA A/B frag)
typedef __attribute__((ext_vector_type(4))) float f32x4;    // MFMA C/D frag

#define BB 4
#define NN 2048
#define DD 256
#define HH 8
#define LAMBDA 0.17677669529f   // 1/sqrt(32), natural-log units (__expf supplies log2e)

__device__ inline u16 bfu(float f) {
  __hip_bfloat16 h = __float2bfloat16(f);
  return *reinterpret_cast<u16*>(&h);
}
__device__ inline bf16x8 asfrag(uint4 v) { return __builtin_bit_cast(bf16x8, v); }

// ---------------- merged prep: x(permuted)+xb, mask->u8, weights ----------------
// xp[row][c*16+j] = x[row][16j+c]  (fragment-friendly layout for the tail kernel)
__global__ __launch_bounds__(256) void prep_kernel(
    const float* __restrict__ qdt, const float* __restrict__ boxes,
    const int* __restrict__ mask,
    const float* __restrict__ Wq, const float* __restrict__ Wk, const float* __restrict__ Wv,
    const float* __restrict__ Wo, const float* __restrict__ W1, const float* __restrict__ W2,
    const float* __restrict__ bq, const float* __restrict__ bk, const float* __restrict__ bv,
    float* __restrict__ xp, u16* __restrict__ xb, unsigned char* __restrict__ m8,
    u16* __restrict__ wqkvT, u16* __restrict__ woT, u16* __restrict__ w1T, u16* __restrict__ w2T,
    float* __restrict__ bqkv) {
  const int bid = blockIdx.x, t = threadIdx.x;
  if (bid < 2048) {                       // x = qdt + boxes (permuted fp32 + linear bf16)
    int i = bid * 256 + t;
    int row = i >> 6, q = i & 63;
    float4 a = ((const float4*)qdt)[i];
    float4 b = ((const float4*)boxes)[i];
    float4 v = make_float4(a.x + b.x, a.y + b.y, a.z + b.z, a.w + b.w);
    ((ushort4*)xb)[i] = make_ushort4(bfu(v.x), bfu(v.y), bfu(v.z), bfu(v.w));
    float* xr = xp + (size_t)row * 256;
    xr[((4*q+0) & 15) * 16 + ((4*q+0) >> 4)] = v.x;
    xr[((4*q+1) & 15) * 16 + ((4*q+1) >> 4)] = v.y;
    xr[((4*q+2) & 15) * 16 + ((4*q+2) >> 4)] = v.z;
    xr[((4*q+3) & 15) * 16 + ((4*q+3) >> 4)] = v.w;
  } else if (bid < 6144) {                // mask int -> u8 0/1
    int i = (bid - 2048) * 256 + t;
    int4 m = ((const int4*)mask)[i];
    ((uchar4*)m8)[i] = make_uchar4((unsigned char)m.x, (unsigned char)m.y,
                                   (unsigned char)m.z, (unsigned char)m.w);
  } else {                                // weight transposes + qkv bias concat
    int i = (bid - 6144) * 256 + t;
    if (i < 196608) {
      int n = i >> 8, k = i & 255;
      const float* src = (n < 256) ? Wq : (n < 512 ? Wk : Wv);
      wqkvT[i] = bfu(src[k * 256 + (n & 255)]);
    } else if (i < 262144) {
      int j = i - 196608; int n = j >> 8, k = j & 255;
      woT[j] = bfu(Wo[k * 256 + n]);
    } else if (i < 327680) {
      int j = i - 262144; int n = j >> 8, k = j & 255;
      w1T[j] = bfu(W1[k * 256 + n]);
    } else if (i < 393216) {
      int j = i - 327680; int n = j >> 8, k = j & 255;
      w2T[j] = bfu(W2[k * 256 + n]);
    } else if (i < 393984) {
      int n = i - 393216;
      bqkv[n] = (n < 256) ? bq[n] : (n < 512 ? bk[n - 256] : bv[n - 512]);
    }
  }
}

// ============ shared GEMM body: C = A[M,256] @ Bt[N,256]^T, 64x64 tile ============
#define GEMM_BODY()                                                              \
  __shared__ u16 At[64][264];                                                    \
  __shared__ u16 Bs[64][264];                                                    \
  const int m0 = blockIdx.x * 64;                                                \
  const int n0 = blockIdx.y * 64;                                                \
  const int t = threadIdx.x;                                                     \
  {                                                                              \
    const int row = t >> 2, cb = (t & 3) * 64;                                   \
    const u16* ga = A  + (size_t)(m0 + row) * 256 + cb;                          \
    const u16* gb = Bt + (size_t)(n0 + row) * 256 + cb;                          \
    _Pragma("unroll")                                                            \
    for (int i = 0; i < 8; ++i) {                                                \
      *(int4*)&At[row][cb + i * 8] = *(const int4*)(ga + i * 8);                 \
      *(int4*)&Bs[row][cb + i * 8] = *(const int4*)(gb + i * 8);                 \
    }                                                                            \
  }                                                                              \
  __syncthreads();                                                               \
  const int w = t >> 6, l = t & 63, g = l >> 4, c = l & 15;                      \
  f32x4 acc[4] = {};                                                             \
  _Pragma("unroll")                                                              \
  for (int kk = 0; kk < 256; kk += 32) {                                         \
    bf16x8 af = *(const bf16x8*)&At[w * 16 + c][kk + g * 8];                     \
    _Pragma("unroll")                                                            \
    for (int j = 0; j < 4; ++j) {                                                \
      bf16x8 bfr = *(const bf16x8*)&Bs[j * 16 + c][kk + g * 8];                  \
      acc[j] = __builtin_amdgcn_mfma_f32_16x16x32_bf16(af, bfr, acc[j], 0, 0, 0);\
    }                                                                            \
  }

// QKV (q,k part): q scaled by LAMBDA -> [8192][256]; k -> [B][H][2048][32]
__global__ __launch_bounds__(256) void gemm_qk_kernel(
    const u16* __restrict__ A, const u16* __restrict__ Bt, const float* __restrict__ bias,
    u16* __restrict__ qout, u16* __restrict__ kout) {
  GEMM_BODY()
  if (n0 < 256) {
#pragma unroll
    for (int j = 0; j < 4; ++j)
#pragma unroll
      for (int r = 0; r < 4; ++r) {
        int m = m0 + w * 16 + g * 4 + r, n = n0 + j * 16 + c;
        qout[(size_t)m * 256 + n] = bfu((acc[j][r] + bias[n]) * LAMBDA);
      }
  } else {
#pragma unroll
    for (int j = 0; j < 4; ++j)
#pragma unroll
      for (int r = 0; r < 4; ++r) {
        int m = m0 + w * 16 + g * 4 + r, n = n0 + j * 16 + c;
        int ch = n - 256;
        kout[(size_t)((m >> 11) * 8 + (ch >> 5)) * 65536 + (size_t)(m & 2047) * 32 + (ch & 31)]
            = bfu(acc[j][r] + bias[n]);
      }
  }
}

// V^T: A = WvT[256][256], Bt = xb[8192][256] -> vT[256][8192], bias by m(channel)
__global__ __launch_bounds__(256) void gemm_vt_kernel(
    const u16* __restrict__ A, const u16* __restrict__ Bt, const float* __restrict__ bias,
    u16* __restrict__ vtout) {
  GEMM_BODY()
#pragma unroll
  for (int j = 0; j < 4; ++j)
#pragma unroll
    for (int r = 0; r < 4; ++r) {
      int m = m0 + w * 16 + g * 4 + r;   // channel
      int n = n0 + j * 16 + c;           // token
      vtout[(size_t)m * 8192 + n] = bfu(acc[j][r] + bias[m]);
    }
}

// ---------------- fused sigmoid-gated attention (round-6 PASSING build) ----------------
__global__ __launch_bounds__(256) void attn_kernel(
    const u16* __restrict__ qb,            // [8192][256] bf16, LAMBDA-scaled
    const u16* __restrict__ kb,            // [B][H][2048][32] bf16
    const u16* __restrict__ vtb,           // [256][8192] bf16 (V^T)
    const unsigned char* __restrict__ m8,  // [2048][2048] 0/1
    u16* __restrict__ ob) {                // [8192][256] bf16
  __shared__ u32 Klds[2][64][20];          // 16 data u32 + 4 pad (row 80 B)
  __shared__ u32 Vlds[2][32][36];          // 32 data u32 + 4 pad (row 144 B)
  __shared__ unsigned char Mlds[2][64][64];// mask tile, byte-rotated rows
  __shared__ u32 Plds[4][16][36];          // 32 data u32 + 4 pad, per-wave

  const int bid = blockIdx.x;
  const int qt = bid & 31, h = (bid >> 5) & 7, b = bid >> 8;
  const int q0 = qt * 64;
  const int t = threadIdx.x, w = t >> 6, l = t & 63, g = l >> 4, c = l & 15;

  const bf16x8 qf = asfrag(*(const uint4*)(qb + (size_t)(b * NN + q0 + 16 * w + c) * 256 + h * 32 + 8 * g));
  f32x4 oacc[2] = {};

  const int srowK = t >> 2, ssegK = t & 3;
  const int srowV = t >> 3, ssegV = t & 7;
  const u16* kg = kb + (size_t)(b * 8 + h) * 65536 + srowK * 32 + ssegK * 8;
  const u16* vg = vtb + (size_t)(h * 32 + srowV) * 8192 + (size_t)b * NN + ssegV * 8;
  const unsigned char* mg = m8 + (size_t)(q0 + srowK) * NN + ssegK * 16;

  const int mb0 = (16 * ssegK + 8 * (srowK & 7)) & 63;
  const int mb1 = (mb0 + 8) & 63;

  uint4 krg = *(const uint4*)kg;
  uint4 vrg = *(const uint4*)vg;
  uint4 mrg = *(const uint4*)mg;
  *(uint4*)&Klds[0][srowK][ssegK * 4] = krg;
  *(uint4*)&Vlds[0][srowV][ssegV * 4] = vrg;
  *(uint2*)&Mlds[0][srowK][mb0] = make_uint2(mrg.x, mrg.y);
  *(uint2*)&Mlds[0][srowK][mb1] = make_uint2(mrg.z, mrg.w);
  __syncthreads();

  const f32x4 zf = {0.f, 0.f, 0.f, 0.f};
  u32* Pw = &Plds[w][0][0];

  for (int it = 0; it < 32; ++it) {
    const int cur = it & 1;
    if (it < 31) {
      const int kt = (it + 1) * 64;
      krg = *(const uint4*)(kg + (size_t)kt * 32);
      vrg = *(const uint4*)(vg + kt);
      mrg = *(const uint4*)(mg + kt);
    }
#pragma unroll
    for (int tt = 0; tt < 4; ++tt) {
      bf16x8 kf = asfrag(*(const uint4*)&Klds[cur][16 * tt + c][4 * g]);
      f32x4 s = __builtin_amdgcn_mfma_f32_16x16x32_bf16(kf, qf, zf, 0, 0, 0);
      u32 mdw = *(const u32*)&Mlds[cur][16 * w + c][(16 * tt + 4 * g + 8 * (c & 7)) & 63];
      float mf0 = (float)(mdw & 0xffu);
      float mf1 = (float)((mdw >> 8) & 0xffu);
      float mf2 = (float)((mdw >> 16) & 0xffu);
      float mf3 = (float)(mdw >> 24);
      float p0 = mf0 * __builtin_amdgcn_rcpf(1.f + __expf(-s[0]));
      float p1 = mf1 * __builtin_amdgcn_rcpf(1.f + __expf(-s[1]));
      float p2 = mf2 * __builtin_amdgcn_rcpf(1.f + __expf(-s[2]));
      float p3 = mf3 * __builtin_amdgcn_rcpf(1.f + __expf(-s[3]));
      u32 w0, w1;
      asm("v_cvt_pk_bf16_f32 %0, %1, %2" : "=v"(w0) : "v"(p0), "v"(p1));
      asm("v_cvt_pk_bf16_f32 %0, %1, %2" : "=v"(w1) : "v"(p2), "v"(p3));
      *(uint2*)&Pw[c * 36 + 8 * tt + 2 * g] = make_uint2(w0, w1);
    }
    asm volatile("s_waitcnt lgkmcnt(0)" ::: "memory");
    __builtin_amdgcn_sched_barrier(0);
#pragma unroll
    for (int kk = 0; kk < 2; ++kk) {
      bf16x8 pf = asfrag(*(const uint4*)&Pw[c * 36 + 16 * kk + 4 * g]);
#pragma unroll
      for (int d0 = 0; d0 < 2; ++d0) {
        bf16x8 vf = asfrag(*(const uint4*)&Vlds[cur][16 * d0 + c][16 * kk + 4 * g]);
        oacc[d0] = __builtin_amdgcn_mfma_f32_16x16x32_bf16(pf, vf, oacc[d0], 0, 0, 0);
      }
    }
    if (it < 31) {
      *(uint4*)&Klds[cur ^ 1][srowK][ssegK * 4] = krg;
      *(uint4*)&Vlds[cur ^ 1][srowV][ssegV * 4] = vrg;
      *(uint2*)&Mlds[cur ^ 1][srowK][mb0] = make_uint2(mrg.x, mrg.y);
      *(uint2*)&Mlds[cur ^ 1][srowK][mb1] = make_uint2(mrg.z, mrg.w);
    }
    __syncthreads();
  }

  const size_t obase = (size_t)(b * NN + q0 + 16 * w) * 256 + h * 32;
#pragma unroll
  for (int d0 = 0; d0 < 2; ++d0)
#pragma unroll
    for (int r = 0; r < 4; ++r)
      ob[obase + (size_t)(4 * g + r) * 256 + 16 * d0 + c] = bfu(oacc[d0][r]);
}

// ---------------- fused tail: Wo+res -> LN1 -> FF1+relu -> FF2+res -> LN2 ----------------
// 512 blocks x 1 wave; wave = 16 rows x full 256 cols -> all LDS wave-local,
// NO barriers, rule-18 fences only. t1 (LN1 output, FF2 residual) lives in LDS
// (T1 f32) instead of 64 VGPRs -- the round-8 build spilled at VGPR=256
// (WRITE_SIZE 29MB of scratch); this keeps peak pressure ~acc[16]+pipeline.
__global__ __launch_bounds__(64) void tail_kernel(
    const u16* __restrict__ obuf, const u16* __restrict__ woT,
    const u16* __restrict__ w1T, const u16* __restrict__ w2T,
    const float* __restrict__ xp,          // [8192][256] f32, permuted [row][c*16+j]
    const float* __restrict__ bo, const float* __restrict__ b1, const float* __restrict__ b2,
    const float* __restrict__ g1, const float* __restrict__ be1,
    const float* __restrict__ g2, const float* __restrict__ be2,
    float* __restrict__ out) {
  __shared__ u16 A[16][264];               // bf16 activation tile (row-padded)
  __shared__ float T1[16][260];            // f32 LN1-output / scratch z
  const int t = threadIdx.x, g = t >> 4, c = t & 15;
  const int m0 = blockIdx.x * 16;          // this wave's 16 rows
  const f32x4 zf4 = {0.f, 0.f, 0.f, 0.f};

  // ---- stage obuf rows m0..m0+15 ----
  {
    const int srow = t >> 2, sseg = t & 3; // 16 rows x 4 lanes; each lane 8 x 16B
#pragma unroll
    for (int i = 0; i < 8; ++i) {
      uint4 v = *(const uint4*)(obuf + (size_t)(m0 + srow) * 256 + (sseg + 4 * i) * 8);
      *(uint4*)&A[srow][(sseg + 4 * i) * 8] = v;
    }
  }
  asm volatile("s_waitcnt lgkmcnt(0)" ::: "memory");
  __builtin_amdgcn_sched_barrier(0);

  f32x4 acc[16];
  float s1[4], s2[4], mean[4], inv[4];

  // ---- GEMM1: obuf @ Wo ----
#pragma unroll
  for (int j = 0; j < 16; ++j) acc[j] = zf4;
#pragma unroll
  for (int kk = 0; kk < 256; kk += 32) {
    bf16x8 af = *(const bf16x8*)&A[c][kk + 8 * g];
#pragma unroll
    for (int j = 0; j < 16; ++j) {
      bf16x8 bfr = asfrag(*(const uint4*)(woT + (size_t)(16 * j + c) * 256 + kk + 8 * g));
      acc[j] = __builtin_amdgcn_mfma_f32_16x16x32_bf16(af, bfr, acc[j], 0, 0, 0);
    }
  }
  // ---- epilogue1: z = acc + bo + x -> T1; LN1 stats in-flight ----
  {
    float bov[16];
#pragma unroll
    for (int j = 0; j < 16; ++j) bov[j] = bo[16 * j + c];
#pragma unroll
    for (int r = 0; r < 4; ++r) {
      const float* xrow = xp + (size_t)(m0 + 4 * g + r) * 256 + c * 16;
      float4 xq0 = ((const float4*)xrow)[0], xq1 = ((const float4*)xrow)[1];
      float4 xq2 = ((const float4*)xrow)[2], xq3 = ((const float4*)xrow)[3];
      float xa[16] = {xq0.x, xq0.y, xq0.z, xq0.w, xq1.x, xq1.y, xq1.z, xq1.w,
                      xq2.x, xq2.y, xq2.z, xq2.w, xq3.x, xq3.y, xq3.z, xq3.w};
      float a1 = 0.f, a2 = 0.f;
#pragma unroll
      for (int j = 0; j < 16; ++j) {
        float z = acc[j][r] + bov[j] + xa[j];
        T1[4 * g + r][16 * j + c] = z;
        a1 += z; a2 += z * z;
      }
      s1[r] = a1; s2[r] = a2;
    }
  }
#pragma unroll
  for (int r = 0; r < 4; ++r) {
#pragma unroll
    for (int off = 1; off < 16; off <<= 1) {
      s1[r] += __shfl_xor(s1[r], off);
      s2[r] += __shfl_xor(s2[r], off);
    }
    mean[r] = s1[r] * (1.f / 256.f);
    inv[r] = rsqrtf(s2[r] * (1.f / 256.f) - mean[r] * mean[r] + 1e-5f);
  }
  // normalize T1 in place (v = LN1 out, kept for FF2 residual) + bf16 tile -> A
  asm volatile("s_waitcnt lgkmcnt(0)" ::: "memory");   // z writes done; A WAR vs GEMM1 reads
  __builtin_amdgcn_sched_barrier(0);
#pragma unroll
  for (int j = 0; j < 16; ++j) {
    const int n = 16 * j + c;
    const float gv = g1[n], bev = be1[n];
#pragma unroll
    for (int r = 0; r < 4; ++r) {
      float v = (T1[4 * g + r][n] - mean[r]) * inv[r] * gv + bev;
      T1[4 * g + r][n] = v;
      A[4 * g + r][n] = bfu(v);
    }
  }
  asm volatile("s_waitcnt lgkmcnt(0)" ::: "memory");
  __builtin_amdgcn_sched_barrier(0);

  // ---- GEMM2: t1 @ W1, relu ----
#pragma unroll
  for (int j = 0; j < 16; ++j) acc[j] = zf4;
#pragma unroll
  for (int kk = 0; kk < 256; kk += 32) {
    bf16x8 af = *(const bf16x8*)&A[c][kk + 8 * g];
#pragma unroll
    for (int j = 0; j < 16; ++j) {
      bf16x8 bfr = asfrag(*(const uint4*)(w1T + (size_t)(16 * j + c) * 256 + kk + 8 * g));
      acc[j] = __builtin_amdgcn_mfma_f32_16x16x32_bf16(af, bfr, acc[j], 0, 0, 0);
    }
  }
  asm volatile("" ::: "memory");       // A WAR: stores below after reads above
  __builtin_amdgcn_sched_barrier(0);
#pragma unroll
  for (int j = 0; j < 16; ++j) {
    const int n = 16 * j + c;
    const float bv = b1[n];
#pragma unroll
    for (int r = 0; r < 4; ++r) {
      float v = acc[j][r] + bv;
      A[4 * g + r][n] = bfu(v > 0.f ? v : 0.f);
    }
  }
  asm volatile("s_waitcnt lgkmcnt(0)" ::: "memory");
  __builtin_amdgcn_sched_barrier(0);

  // ---- GEMM3: h @ W2 ----
#pragma unroll
  for (int j = 0; j < 16; ++j) acc[j] = zf4;
#pragma unroll
  for (int kk = 0; kk < 256; kk += 32) {
    bf16x8 af = *(const bf16x8*)&A[c][kk + 8 * g];
#pragma unroll
    for (int j = 0; j < 16; ++j) {
      bf16x8 bfr = asfrag(*(const uint4*)(w2T + (size_t)(16 * j + c) * 256 + kk + 8 * g));
      acc[j] = __builtin_amdgcn_mfma_f32_16x16x32_bf16(af, bfr, acc[j], 0, 0, 0);
    }
  }
  // ---- epilogue3: z = acc + b2 + t1(T1); LN2 -> out ----
  {
    float b2v[16];
#pragma unroll
    for (int j = 0; j < 16; ++j) b2v[j] = b2[16 * j + c];
#pragma unroll
    for (int r = 0; r < 4; ++r) {
      float a1 = 0.f, a2 = 0.f;
#pragma unroll
      for (int j = 0; j < 16; ++j) {
        float z = acc[j][r] + b2v[j] + T1[4 * g + r][16 * j + c];
        T1[4 * g + r][16 * j + c] = z;
        a1 += z; a2 += z * z;
      }
      s1[r] = a1; s2[r] = a2;
    }
  }
#pragma unroll
  for (int r = 0; r < 4; ++r) {
#pragma unroll
    for (int off = 1; off < 16; off <<= 1) {
      s1[r] += __shfl_xor(s1[r], off);
      s2[r] += __shfl_xor(s2[r], off);
    }
    mean[r] = s1[r] * (1.f / 256.f);
    inv[r] = rsqrtf(s2[r] * (1.f / 256.f) - mean[r] * mean[r] + 1e-5f);
  }
  asm volatile("s_waitcnt lgkmcnt(0)" ::: "memory");
  __builtin_amdgcn_sched_barrier(0);
#pragma unroll
  for (int j = 0; j < 16; ++j) {
    const int n = 16 * j + c;
    const float gv = g2[n], bev = be2[n];
#pragma unroll
    for (int r = 0; r < 4; ++r)
      out[(size_t)(m0 + 4 * g + r) * 256 + n] = (T1[4 * g + r][n] - mean[r]) * inv[r] * gv + bev;
  }
}

extern "C" void kernel_launch(void* const* d_in, const int* in_sizes, int n_in,
                              void* d_out, int out_size, void* d_ws, size_t ws_size,
                              hipStream_t stream) {
  const float* qdt   = (const float*)d_in[0];
  const float* boxes = (const float*)d_in[1];
  const int*   mask  = (const int*)d_in[2];
  const float* Wq = (const float*)d_in[3];
  const float* bq = (const float*)d_in[4];
  const float* Wk = (const float*)d_in[5];
  const float* bk = (const float*)d_in[6];
  const float* Wv = (const float*)d_in[7];
  const float* bv = (const float*)d_in[8];
  const float* Wo = (const float*)d_in[9];
  const float* bo = (const float*)d_in[10];
  const float* W1 = (const float*)d_in[11];
  const float* b1 = (const float*)d_in[12];
  const float* W2 = (const float*)d_in[13];
  const float* b2 = (const float*)d_in[14];
  const float* g1  = (const float*)d_in[15];
  const float* be1 = (const float*)d_in[16];
  const float* g2  = (const float*)d_in[17];
  const float* be2 = (const float*)d_in[18];

  char* ws = (char*)d_ws;
  float* xp    = (float*)(ws + 0);          // [8192,256] f32 permuted residual
  u16*   xb    = (u16*)  (ws + 8388608);
  u16*   qbuf  = (u16*)  (ws + 12582912);   // q, LAMBDA-scaled
  u16*   kbuf  = (u16*)  (ws + 16777216);   // [B][H][2048][32]
  u16*   vtbuf = (u16*)  (ws + 20971520);   // [256][8192]
  u16*   obuf  = (u16*)  (ws + 25165824);
  u16*   wqkvT = (u16*)  (ws + 46137344);   // [768,256]
  u16*   woT   = (u16*)  (ws + 46530560);
  u16*   w1T   = (u16*)  (ws + 46661632);
  u16*   w2T   = (u16*)  (ws + 46792704);
  float* bqkv  = (float*)(ws + 46923776);
  unsigned char* m8 = (unsigned char*)(ws + 46926848);  // [2048,2048] u8

  // merged prep: xp/xb (2048 blk) + mask->m8 (4096 blk) + weights (1539 blk)
  prep_kernel<<<7683, 256, 0, stream>>>(qdt, boxes, mask, Wq, Wk, Wv, Wo, W1, W2,
                                        bq, bk, bv, xp, xb, m8,
                                        wqkvT, woT, w1T, w2T, bqkv);
  // Q (scaled) + K (relayout): [8192,256] x [256,512]
  gemm_qk_kernel<<<dim3(128, 8), 256, 0, stream>>>(xb, wqkvT, bqkv, qbuf, kbuf);
  // V^T: [256,256] x [256,8192]^T
  gemm_vt_kernel<<<dim3(4, 128), 256, 0, stream>>>(wqkvT + 512 * 256, xb, bqkv + 512, vtbuf);
  // attention
  attn_kernel<<<1024, 256, 0, stream>>>(qbuf, kbuf, vtbuf, m8, obuf);
  // fused tail: Wo+res -> LN1 -> FF1+relu -> FF2+res -> LN2 -> d_out
  tail_kernel<<<512, 64, 0, stream>>>(obuf, woT, w1T, w2T, xp,
                                      bo, b1, b2, g1, be1, g2, be2, (float*)d_out);
}

// Round 10
// 117.557 us; speedup vs baseline: 1.6181x; 1.0918x over previous
//
#include <hip/hip_runtime.h>
#include <hip/hip_bf16.h>

typedef unsigned short u16;
typedef unsigned int u32;
typedef __attribute__((ext_vector_type(8))) short bf16x8;   // 8 bf16 = 4 VGPRs (MFMA A/B frag)
typedef __attribute__((ext_vector_type(4))) float f32x4;    // MFMA C/D frag

#define BB 4
#define NN 2048
#define DD 256
#define HH 8
#define LAMBDA 0.17677669529f   // 1/sqrt(32), natural-log units (__expf supplies log2e)

__device__ inline u16 bfu(float f) {
  __hip_bfloat16 h = __float2bfloat16(f);
  return *reinterpret_cast<u16*>(&h);
}
__device__ inline bf16x8 asfrag(uint4 v) { return __builtin_bit_cast(bf16x8, v); }

// ---------------- merged prep: x(permuted)+xb, mask->u8, weights ----------------
// xp[row][c*16+j] = x[row][16j+c]  (fragment-friendly layout for the tail kernel)
__global__ __launch_bounds__(256) void prep_kernel(
    const float* __restrict__ qdt, const float* __restrict__ boxes,
    const int* __restrict__ mask,
    const float* __restrict__ Wq, const float* __restrict__ Wk, const float* __restrict__ Wv,
    const float* __restrict__ Wo, const float* __restrict__ W1, const float* __restrict__ W2,
    const float* __restrict__ bq, const float* __restrict__ bk, const float* __restrict__ bv,
    float* __restrict__ xp, u16* __restrict__ xb, unsigned char* __restrict__ m8,
    u16* __restrict__ wqkvT, u16* __restrict__ woT, u16* __restrict__ w1T, u16* __restrict__ w2T,
    float* __restrict__ bqkv) {
  const int bid = blockIdx.x, t = threadIdx.x;
  if (bid < 2048) {                       // x = qdt + boxes (permuted fp32 + linear bf16)
    int i = bid * 256 + t;
    int row = i >> 6, q = i & 63;
    float4 a = ((const float4*)qdt)[i];
    float4 b = ((const float4*)boxes)[i];
    float4 v = make_float4(a.x + b.x, a.y + b.y, a.z + b.z, a.w + b.w);
    ((ushort4*)xb)[i] = make_ushort4(bfu(v.x), bfu(v.y), bfu(v.z), bfu(v.w));
    float* xr = xp + (size_t)row * 256;
    xr[((4*q+0) & 15) * 16 + ((4*q+0) >> 4)] = v.x;
    xr[((4*q+1) & 15) * 16 + ((4*q+1) >> 4)] = v.y;
    xr[((4*q+2) & 15) * 16 + ((4*q+2) >> 4)] = v.z;
    xr[((4*q+3) & 15) * 16 + ((4*q+3) >> 4)] = v.w;
  } else if (bid < 6144) {                // mask int -> u8 0/1
    int i = (bid - 2048) * 256 + t;
    int4 m = ((const int4*)mask)[i];
    ((uchar4*)m8)[i] = make_uchar4((unsigned char)m.x, (unsigned char)m.y,
                                   (unsigned char)m.z, (unsigned char)m.w);
  } else {                                // weight transposes + qkv bias concat
    int i = (bid - 6144) * 256 + t;
    if (i < 196608) {
      int n = i >> 8, k = i & 255;
      const float* src = (n < 256) ? Wq : (n < 512 ? Wk : Wv);
      wqkvT[i] = bfu(src[k * 256 + (n & 255)]);
    } else if (i < 262144) {
      int j = i - 196608; int n = j >> 8, k = j & 255;
      woT[j] = bfu(Wo[k * 256 + n]);
    } else if (i < 327680) {
      int j = i - 262144; int n = j >> 8, k = j & 255;
      w1T[j] = bfu(W1[k * 256 + n]);
    } else if (i < 393216) {
      int j = i - 327680; int n = j >> 8, k = j & 255;
      w2T[j] = bfu(W2[k * 256 + n]);
    } else if (i < 393984) {
      int n = i - 393216;
      bqkv[n] = (n < 256) ? bq[n] : (n < 512 ? bk[n - 256] : bv[n - 512]);
    }
  }
}

// ============ shared GEMM body: C = A[M,256] @ Bt[N,256]^T, 64x64 tile ============
#define GEMM_BODY()                                                              \
  __shared__ u16 At[64][264];                                                    \
  __shared__ u16 Bs[64][264];                                                    \
  const int m0 = blockIdx.x * 64;                                                \
  const int n0 = blockIdx.y * 64;                                                \
  const int t = threadIdx.x;                                                     \
  {                                                                              \
    const int row = t >> 2, cb = (t & 3) * 64;                                   \
    const u16* ga = A  + (size_t)(m0 + row) * 256 + cb;                          \
    const u16* gb = Bt + (size_t)(n0 + row) * 256 + cb;                          \
    _Pragma("unroll")                                                            \
    for (int i = 0; i < 8; ++i) {                                                \
      *(int4*)&At[row][cb + i * 8] = *(const int4*)(ga + i * 8);                 \
      *(int4*)&Bs[row][cb + i * 8] = *(const int4*)(gb + i * 8);                 \
    }                                                                            \
  }                                                                              \
  __syncthreads();                                                               \
  const int w = t >> 6, l = t & 63, g = l >> 4, c = l & 15;                      \
  f32x4 acc[4] = {};                                                             \
  _Pragma("unroll")                                                              \
  for (int kk = 0; kk < 256; kk += 32) {                                         \
    bf16x8 af = *(const bf16x8*)&At[w * 16 + c][kk + g * 8];                     \
    _Pragma("unroll")                                                            \
    for (int j = 0; j < 4; ++j) {                                                \
      bf16x8 bfr = *(const bf16x8*)&Bs[j * 16 + c][kk + g * 8];                  \
      acc[j] = __builtin_amdgcn_mfma_f32_16x16x32_bf16(af, bfr, acc[j], 0, 0, 0);\
    }                                                                            \
  }

// QKV (q,k part): q scaled by LAMBDA -> [8192][256]; k -> [B][H][2048][32]
__global__ __launch_bounds__(256) void gemm_qk_kernel(
    const u16* __restrict__ A, const u16* __restrict__ Bt, const float* __restrict__ bias,
    u16* __restrict__ qout, u16* __restrict__ kout) {
  GEMM_BODY()
  if (n0 < 256) {
#pragma unroll
    for (int j = 0; j < 4; ++j)
#pragma unroll
      for (int r = 0; r < 4; ++r) {
        int m = m0 + w * 16 + g * 4 + r, n = n0 + j * 16 + c;
        qout[(size_t)m * 256 + n] = bfu((acc[j][r] + bias[n]) * LAMBDA);
      }
  } else {
#pragma unroll
    for (int j = 0; j < 4; ++j)
#pragma unroll
      for (int r = 0; r < 4; ++r) {
        int m = m0 + w * 16 + g * 4 + r, n = n0 + j * 16 + c;
        int ch = n - 256;
        kout[(size_t)((m >> 11) * 8 + (ch >> 5)) * 65536 + (size_t)(m & 2047) * 32 + (ch & 31)]
            = bfu(acc[j][r] + bias[n]);
      }
  }
}

// V^T: A = WvT[256][256], Bt = xb[8192][256] -> vT[256][8192], bias by m(channel)
__global__ __launch_bounds__(256) void gemm_vt_kernel(
    const u16* __restrict__ A, const u16* __restrict__ Bt, const float* __restrict__ bias,
    u16* __restrict__ vtout) {
  GEMM_BODY()
#pragma unroll
  for (int j = 0; j < 4; ++j)
#pragma unroll
    for (int r = 0; r < 4; ++r) {
      int m = m0 + w * 16 + g * 4 + r;   // channel
      int n = n0 + j * 16 + c;           // token
      vtout[(size_t)m * 8192 + n] = bfu(acc[j][r] + bias[m]);
    }
}

// ---------------- fused sigmoid-gated attention (round-6 PASSING build) ----------------
__global__ __launch_bounds__(256) void attn_kernel(
    const u16* __restrict__ qb,            // [8192][256] bf16, LAMBDA-scaled
    const u16* __restrict__ kb,            // [B][H][2048][32] bf16
    const u16* __restrict__ vtb,           // [256][8192] bf16 (V^T)
    const unsigned char* __restrict__ m8,  // [2048][2048] 0/1
    u16* __restrict__ ob) {                // [8192][256] bf16
  __shared__ u32 Klds[2][64][20];          // 16 data u32 + 4 pad (row 80 B)
  __shared__ u32 Vlds[2][32][36];          // 32 data u32 + 4 pad (row 144 B)
  __shared__ unsigned char Mlds[2][64][64];// mask tile, byte-rotated rows
  __shared__ u32 Plds[4][16][36];          // 32 data u32 + 4 pad, per-wave

  const int bid = blockIdx.x;
  const int qt = bid & 31, h = (bid >> 5) & 7, b = bid >> 8;
  const int q0 = qt * 64;
  const int t = threadIdx.x, w = t >> 6, l = t & 63, g = l >> 4, c = l & 15;

  const bf16x8 qf = asfrag(*(const uint4*)(qb + (size_t)(b * NN + q0 + 16 * w + c) * 256 + h * 32 + 8 * g));
  f32x4 oacc[2] = {};

  const int srowK = t >> 2, ssegK = t & 3;
  const int srowV = t >> 3, ssegV = t & 7;
  const u16* kg = kb + (size_t)(b * 8 + h) * 65536 + srowK * 32 + ssegK * 8;
  const u16* vg = vtb + (size_t)(h * 32 + srowV) * 8192 + (size_t)b * NN + ssegV * 8;
  const unsigned char* mg = m8 + (size_t)(q0 + srowK) * NN + ssegK * 16;

  const int mb0 = (16 * ssegK + 8 * (srowK & 7)) & 63;
  const int mb1 = (mb0 + 8) & 63;

  uint4 krg = *(const uint4*)kg;
  uint4 vrg = *(const uint4*)vg;
  uint4 mrg = *(const uint4*)mg;
  *(uint4*)&Klds[0][srowK][ssegK * 4] = krg;
  *(uint4*)&Vlds[0][srowV][ssegV * 4] = vrg;
  *(uint2*)&Mlds[0][srowK][mb0] = make_uint2(mrg.x, mrg.y);
  *(uint2*)&Mlds[0][srowK][mb1] = make_uint2(mrg.z, mrg.w);
  __syncthreads();

  const f32x4 zf = {0.f, 0.f, 0.f, 0.f};
  u32* Pw = &Plds[w][0][0];

  for (int it = 0; it < 32; ++it) {
    const int cur = it & 1;
    if (it < 31) {
      const int kt = (it + 1) * 64;
      krg = *(const uint4*)(kg + (size_t)kt * 32);
      vrg = *(const uint4*)(vg + kt);
      mrg = *(const uint4*)(mg + kt);
    }
#pragma unroll
    for (int tt = 0; tt < 4; ++tt) {
      bf16x8 kf = asfrag(*(const uint4*)&Klds[cur][16 * tt + c][4 * g]);
      f32x4 s = __builtin_amdgcn_mfma_f32_16x16x32_bf16(kf, qf, zf, 0, 0, 0);
      u32 mdw = *(const u32*)&Mlds[cur][16 * w + c][(16 * tt + 4 * g + 8 * (c & 7)) & 63];
      float mf0 = (float)(mdw & 0xffu);
      float mf1 = (float)((mdw >> 8) & 0xffu);
      float mf2 = (float)((mdw >> 16) & 0xffu);
      float mf3 = (float)(mdw >> 24);
      float p0 = mf0 * __builtin_amdgcn_rcpf(1.f + __expf(-s[0]));
      float p1 = mf1 * __builtin_amdgcn_rcpf(1.f + __expf(-s[1]));
      float p2 = mf2 * __builtin_amdgcn_rcpf(1.f + __expf(-s[2]));
      float p3 = mf3 * __builtin_amdgcn_rcpf(1.f + __expf(-s[3]));
      u32 w0, w1;
      asm("v_cvt_pk_bf16_f32 %0, %1, %2" : "=v"(w0) : "v"(p0), "v"(p1));
      asm("v_cvt_pk_bf16_f32 %0, %1, %2" : "=v"(w1) : "v"(p2), "v"(p3));
      *(uint2*)&Pw[c * 36 + 8 * tt + 2 * g] = make_uint2(w0, w1);
    }
    asm volatile("s_waitcnt lgkmcnt(0)" ::: "memory");
    __builtin_amdgcn_sched_barrier(0);
#pragma unroll
    for (int kk = 0; kk < 2; ++kk) {
      bf16x8 pf = asfrag(*(const uint4*)&Pw[c * 36 + 16 * kk + 4 * g]);
#pragma unroll
      for (int d0 = 0; d0 < 2; ++d0) {
        bf16x8 vf = asfrag(*(const uint4*)&Vlds[cur][16 * d0 + c][16 * kk + 4 * g]);
        oacc[d0] = __builtin_amdgcn_mfma_f32_16x16x32_bf16(pf, vf, oacc[d0], 0, 0, 0);
      }
    }
    if (it < 31) {
      *(uint4*)&Klds[cur ^ 1][srowK][ssegK * 4] = krg;
      *(uint4*)&Vlds[cur ^ 1][srowV][ssegV * 4] = vrg;
      *(uint2*)&Mlds[cur ^ 1][srowK][mb0] = make_uint2(mrg.x, mrg.y);
      *(uint2*)&Mlds[cur ^ 1][srowK][mb1] = make_uint2(mrg.z, mrg.w);
    }
    __syncthreads();
  }

  const size_t obase = (size_t)(b * NN + q0 + 16 * w) * 256 + h * 32;
#pragma unroll
  for (int d0 = 0; d0 < 2; ++d0)
#pragma unroll
    for (int r = 0; r < 4; ++r)
      ob[obase + (size_t)(4 * g + r) * 256 + 16 * d0 + c] = bfu(oacc[d0][r]);
}

// ---------------- fused tail: Wo+res -> LN1 -> FF1+relu -> FF2+res -> LN2 ----------------
// 512 blocks x 4 waves; block = 16 rows, wave w = cols [64w,64w+64) (j in [0,4)).
// 2048 waves = 8/CU (round-9's 1-wave/block build was 2/CU latency-starved).
// LN stats: in-wave shfl_xor over c + cross-wave PS[16][4] + __syncthreads
// (full fence -- replaces the rule-18 inline fences).
__global__ __launch_bounds__(256) void tail_kernel(
    const u16* __restrict__ obuf, const u16* __restrict__ woT,
    const u16* __restrict__ w1T, const u16* __restrict__ w2T,
    const float* __restrict__ xp,          // [8192][256] f32, permuted [row][c*16+j16]
    const float* __restrict__ bo, const float* __restrict__ b1, const float* __restrict__ b2,
    const float* __restrict__ g1, const float* __restrict__ be1,
    const float* __restrict__ g2, const float* __restrict__ be2,
    float* __restrict__ out) {
  __shared__ u16 A[16][264];               // bf16 activation tile
  __shared__ float T1[16][260];            // f32 LN1-output / scratch z
  __shared__ float PS1[16][4], PS2[16][4]; // cross-wave LN partials
  const int t = threadIdx.x, w = t >> 6, l = t & 63, g = l >> 4, c = l & 15;
  const int m0 = blockIdx.x * 16;          // block's 16 rows
  const int n0 = w * 64;                   // wave's 64 cols
  const f32x4 zf4 = {0.f, 0.f, 0.f, 0.f};

  // ---- stage obuf rows m0..m0+15 (256 threads, 2 x 16B each) ----
  {
    const int srow = t >> 4, sseg = t & 15;
#pragma unroll
    for (int i = 0; i < 2; ++i) {
      uint4 v = *(const uint4*)(obuf + (size_t)(m0 + srow) * 256 + (sseg + 16 * i) * 8);
      *(uint4*)&A[srow][(sseg + 16 * i) * 8] = v;
    }
  }
  __syncthreads();

  f32x4 acc[4];
  float mean[4], inv[4];

  // ---- GEMM1: obuf @ Wo (wave's 64 cols) ----
#pragma unroll
  for (int j = 0; j < 4; ++j) acc[j] = zf4;
#pragma unroll
  for (int kk = 0; kk < 256; kk += 32) {
    bf16x8 af = *(const bf16x8*)&A[c][kk + 8 * g];
#pragma unroll
    for (int j = 0; j < 4; ++j) {
      bf16x8 bfr = asfrag(*(const uint4*)(woT + (size_t)(n0 + 16 * j + c) * 256 + kk + 8 * g));
      acc[j] = __builtin_amdgcn_mfma_f32_16x16x32_bf16(af, bfr, acc[j], 0, 0, 0);
    }
  }
  // ---- epilogue1: z = acc + bo + x -> T1, wave partial stats -> PS ----
  {
    float bov[4];
#pragma unroll
    for (int j = 0; j < 4; ++j) bov[j] = bo[n0 + 16 * j + c];
#pragma unroll
    for (int r = 0; r < 4; ++r) {
      float4 xq = ((const float4*)(xp + (size_t)(m0 + 4 * g + r) * 256 + c * 16))[w];
      float xa[4] = {xq.x, xq.y, xq.z, xq.w};
      float a1 = 0.f, a2 = 0.f;
#pragma unroll
      for (int j = 0; j < 4; ++j) {
        float z = acc[j][r] + bov[j] + xa[j];
        T1[4 * g + r][n0 + 16 * j + c] = z;
        a1 += z; a2 += z * z;
      }
#pragma unroll
      for (int off = 1; off < 16; off <<= 1) {
        a1 += __shfl_xor(a1, off);
        a2 += __shfl_xor(a2, off);
      }
      if (c == 0) { PS1[4 * g + r][w] = a1; PS2[4 * g + r][w] = a2; }
    }
  }
  __syncthreads();
#pragma unroll
  for (int r = 0; r < 4; ++r) {
    const int row = 4 * g + r;
    float s1 = PS1[row][0] + PS1[row][1] + PS1[row][2] + PS1[row][3];
    float s2 = PS2[row][0] + PS2[row][1] + PS2[row][2] + PS2[row][3];
    mean[r] = s1 * (1.f / 256.f);
    inv[r] = rsqrtf(s2 * (1.f / 256.f) - mean[r] * mean[r] + 1e-5f);
  }
  // normalize T1 in place (LN1 out, kept for FF2 residual) + bf16 tile -> A
#pragma unroll
  for (int j = 0; j < 4; ++j) {
    const int n = n0 + 16 * j + c;
    const float gv = g1[n], bev = be1[n];
#pragma unroll
    for (int r = 0; r < 4; ++r) {
      float v = (T1[4 * g + r][n] - mean[r]) * inv[r] * gv + bev;
      T1[4 * g + r][n] = v;
      A[4 * g + r][n] = bfu(v);
    }
  }
  __syncthreads();

  // ---- GEMM2: t1 @ W1, relu ----
#pragma unroll
  for (int j = 0; j < 4; ++j) acc[j] = zf4;
#pragma unroll
  for (int kk = 0; kk < 256; kk += 32) {
    bf16x8 af = *(const bf16x8*)&A[c][kk + 8 * g];
#pragma unroll
    for (int j = 0; j < 4; ++j) {
      bf16x8 bfr = asfrag(*(const uint4*)(w1T + (size_t)(n0 + 16 * j + c) * 256 + kk + 8 * g));
      acc[j] = __builtin_amdgcn_mfma_f32_16x16x32_bf16(af, bfr, acc[j], 0, 0, 0);
    }
  }
  __syncthreads();                         // all waves done reading A
#pragma unroll
  for (int j = 0; j < 4; ++j) {
    const int n = n0 + 16 * j + c;
    const float bv = b1[n];
#pragma unroll
    for (int r = 0; r < 4; ++r) {
      float v = acc[j][r] + bv;
      A[4 * g + r][n] = bfu(v > 0.f ? v : 0.f);
    }
  }
  __syncthreads();

  // ---- GEMM3: h @ W2 ----
#pragma unroll
  for (int j = 0; j < 4; ++j) acc[j] = zf4;
#pragma unroll
  for (int kk = 0; kk < 256; kk += 32) {
    bf16x8 af = *(const bf16x8*)&A[c][kk + 8 * g];
#pragma unroll
    for (int j = 0; j < 4; ++j) {
      bf16x8 bfr = asfrag(*(const uint4*)(w2T + (size_t)(n0 + 16 * j + c) * 256 + kk + 8 * g));
      acc[j] = __builtin_amdgcn_mfma_f32_16x16x32_bf16(af, bfr, acc[j], 0, 0, 0);
    }
  }
  // ---- epilogue3: z = acc + b2 + t1; LN2 -> out ----
  {
    float b2v[4];
#pragma unroll
    for (int j = 0; j < 4; ++j) b2v[j] = b2[n0 + 16 * j + c];
#pragma unroll
    for (int r = 0; r < 4; ++r) {
      float a1 = 0.f, a2 = 0.f;
#pragma unroll
      for (int j = 0; j < 4; ++j) {
        const int n = n0 + 16 * j + c;
        float z = acc[j][r] + b2v[j] + T1[4 * g + r][n];
        T1[4 * g + r][n] = z;
        a1 += z; a2 += z * z;
      }
#pragma unroll
      for (int off = 1; off < 16; off <<= 1) {
        a1 += __shfl_xor(a1, off);
        a2 += __shfl_xor(a2, off);
      }
      if (c == 0) { PS1[4 * g + r][w] = a1; PS2[4 * g + r][w] = a2; }
    }
  }
  __syncthreads();
#pragma unroll
  for (int r = 0; r < 4; ++r) {
    const int row = 4 * g + r;
    float s1 = PS1[row][0] + PS1[row][1] + PS1[row][2] + PS1[row][3];
    float s2 = PS2[row][0] + PS2[row][1] + PS2[row][2] + PS2[row][3];
    mean[r] = s1 * (1.f / 256.f);
    inv[r] = rsqrtf(s2 * (1.f / 256.f) - mean[r] * mean[r] + 1e-5f);
  }
#pragma unroll
  for (int j = 0; j < 4; ++j) {
    const int n = n0 + 16 * j + c;
    const float gv = g2[n], bev = be2[n];
#pragma unroll
    for (int r = 0; r < 4; ++r)
      out[(size_t)(m0 + 4 * g + r) * 256 + n] = (T1[4 * g + r][n] - mean[r]) * inv[r] * gv + bev;
  }
}

extern "C" void kernel_launch(void* const* d_in, const int* in_sizes, int n_in,
                              void* d_out, int out_size, void* d_ws, size_t ws_size,
                              hipStream_t stream) {
  const float* qdt   = (const float*)d_in[0];
  const float* boxes = (const float*)d_in[1];
  const int*   mask  = (const int*)d_in[2];
  const float* Wq = (const float*)d_in[3];
  const float* bq = (const float*)d_in[4];
  const float* Wk = (const float*)d_in[5];
  const float* bk = (const float*)d_in[6];
  const float* Wv = (const float*)d_in[7];
  const float* bv = (const float*)d_in[8];
  const float* Wo = (const float*)d_in[9];
  const float* bo = (const float*)d_in[10];
  const float* W1 = (const float*)d_in[11];
  const float* b1 = (const float*)d_in[12];
  const float* W2 = (const float*)d_in[13];
  const float* b2 = (const float*)d_in[14];
  const float* g1  = (const float*)d_in[15];
  const float* be1 = (const float*)d_in[16];
  const float* g2  = (const float*)d_in[17];
  const float* be2 = (const float*)d_in[18];

  char* ws = (char*)d_ws;
  float* xp    = (float*)(ws + 0);          // [8192,256] f32 permuted residual
  u16*   xb    = (u16*)  (ws + 8388608);
  u16*   qbuf  = (u16*)  (ws + 12582912);   // q, LAMBDA-scaled
  u16*   kbuf  = (u16*)  (ws + 16777216);   // [B][H][2048][32]
  u16*   vtbuf = (u16*)  (ws + 20971520);   // [256][8192]
  u16*   obuf  = (u16*)  (ws + 25165824);
  u16*   wqkvT = (u16*)  (ws + 46137344);   // [768,256]
  u16*   woT   = (u16*)  (ws + 46530560);
  u16*   w1T   = (u16*)  (ws + 46661632);
  u16*   w2T   = (u16*)  (ws + 46792704);
  float* bqkv  = (float*)(ws + 46923776);
  unsigned char* m8 = (unsigned char*)(ws + 46926848);  // [2048,2048] u8

  // merged prep: xp/xb (2048 blk) + mask->m8 (4096 blk) + weights (1539 blk)
  prep_kernel<<<7683, 256, 0, stream>>>(qdt, boxes, mask, Wq, Wk, Wv, Wo, W1, W2,
                                        bq, bk, bv, xp, xb, m8,
                                        wqkvT, woT, w1T, w2T, bqkv);
  // Q (scaled) + K (relayout): [8192,256] x [256,512]
  gemm_qk_kernel<<<dim3(128, 8), 256, 0, stream>>>(xb, wqkvT, bqkv, qbuf, kbuf);
  // V^T: [256,256] x [256,8192]^T
  gemm_vt_kernel<<<dim3(4, 128), 256, 0, stream>>>(wqkvT + 512 * 256, xb, bqkv + 512, vtbuf);
  // attention
  attn_kernel<<<1024, 256, 0, stream>>>(qbuf, kbuf, vtbuf, m8, obuf);
  // fused tail: Wo+res -> LN1 -> FF1+relu -> FF2+res -> LN2 -> d_out
  tail_kernel<<<512, 256, 0, stream>>>(obuf, woT, w1T, w2T, xp,
                                       bo, b1, b2, g1, be1, g2, be2, (float*)d_out);
}

// Round 11
// 112.934 us; speedup vs baseline: 1.6843x; 1.0409x over previous
//
#include <hip/hip_runtime.h>
#include <hip/hip_bf16.h>

typedef unsigned short u16;
typedef unsigned int u32;
typedef __attribute__((ext_vector_type(8))) short bf16x8;   // 8 bf16 = 4 VGPRs (MFMA A/B frag)
typedef __attribute__((ext_vector_type(4))) float f32x4;    // MFMA C/D frag

#define BB 4
#define NN 2048
#define DD 256
#define HH 8
#define LAMBDA (-0.2550351f)  // -log2(e)/sqrt(32): folded into Q so sigmoid = rcp(1+exp2(s))

__device__ inline u16 bfu(float f) {
  __hip_bfloat16 h = __float2bfloat16(f);
  return *reinterpret_cast<u16*>(&h);
}
__device__ inline bf16x8 asfrag(uint4 v) { return __builtin_bit_cast(bf16x8, v); }

// ---------------- merged prep: x(permuted)+xb, mask->u8, weights ----------------
// xp[row][c*16+j] = x[row][16j+c]  (fragment-friendly layout for the tail kernel)
__global__ __launch_bounds__(256) void prep_kernel(
    const float* __restrict__ qdt, const float* __restrict__ boxes,
    const int* __restrict__ mask,
    const float* __restrict__ Wq, const float* __restrict__ Wk, const float* __restrict__ Wv,
    const float* __restrict__ Wo, const float* __restrict__ W1, const float* __restrict__ W2,
    const float* __restrict__ bq, const float* __restrict__ bk, const float* __restrict__ bv,
    float* __restrict__ xp, u16* __restrict__ xb, unsigned char* __restrict__ m8,
    u16* __restrict__ wqkvT, u16* __restrict__ woT, u16* __restrict__ w1T, u16* __restrict__ w2T,
    float* __restrict__ bqkv) {
  const int bid = blockIdx.x, t = threadIdx.x;
  if (bid < 2048) {                       // x = qdt + boxes (permuted fp32 + linear bf16)
    int i = bid * 256 + t;
    int row = i >> 6, q = i & 63;
    float4 a = ((const float4*)qdt)[i];
    float4 b = ((const float4*)boxes)[i];
    float4 v = make_float4(a.x + b.x, a.y + b.y, a.z + b.z, a.w + b.w);
    ((ushort4*)xb)[i] = make_ushort4(bfu(v.x), bfu(v.y), bfu(v.z), bfu(v.w));
    float* xr = xp + (size_t)row * 256;
    xr[((4*q+0) & 15) * 16 + ((4*q+0) >> 4)] = v.x;
    xr[((4*q+1) & 15) * 16 + ((4*q+1) >> 4)] = v.y;
    xr[((4*q+2) & 15) * 16 + ((4*q+2) >> 4)] = v.z;
    xr[((4*q+3) & 15) * 16 + ((4*q+3) >> 4)] = v.w;
  } else if (bid < 6144) {                // mask int -> u8 0/1
    int i = (bid - 2048) * 256 + t;
    int4 m = ((const int4*)mask)[i];
    ((uchar4*)m8)[i] = make_uchar4((unsigned char)m.x, (unsigned char)m.y,
                                   (unsigned char)m.z, (unsigned char)m.w);
  } else {                                // weight transposes + qkv bias concat
    int i = (bid - 6144) * 256 + t;
    if (i < 196608) {
      int n = i >> 8, k = i & 255;
      const float* src = (n < 256) ? Wq : (n < 512 ? Wk : Wv);
      wqkvT[i] = bfu(src[k * 256 + (n & 255)]);
    } else if (i < 262144) {
      int j = i - 196608; int n = j >> 8, k = j & 255;
      woT[j] = bfu(Wo[k * 256 + n]);
    } else if (i < 327680) {
      int j = i - 262144; int n = j >> 8, k = j & 255;
      w1T[j] = bfu(W1[k * 256 + n]);
    } else if (i < 393216) {
      int j = i - 327680; int n = j >> 8, k = j & 255;
      w2T[j] = bfu(W2[k * 256 + n]);
    } else if (i < 393984) {
      int n = i - 393216;
      bqkv[n] = (n < 256) ? bq[n] : (n < 512 ? bk[n - 256] : bv[n - 512]);
    }
  }
}

// ---------------- fused QKV-side GEMM: Q(scaled)+K(relayout) and V^T in one launch -------
// bid < 1024 : qk path, 64x64 tile of xb[8192,256] @ wqkvT[512 rows]
// bid >= 1024: vt path, 64x64 tile of WvT[256,256] @ xb^T -> vT[256][8192]
__global__ __launch_bounds__(256) void gemm_qkvt_kernel(
    const u16* __restrict__ xb, const u16* __restrict__ wqkvT,
    const float* __restrict__ bqkv,
    u16* __restrict__ qout, u16* __restrict__ kout, u16* __restrict__ vtout) {
  __shared__ u16 At[64][264];
  __shared__ u16 Bs[64][264];
  const int bid = blockIdx.x;
  const bool isqk = bid < 1024;
  const u16* A  = isqk ? xb : (wqkvT + 512 * 256);
  const u16* Bt = isqk ? wqkvT : xb;
  const int m0 = isqk ? (bid >> 3) * 64 : ((bid - 1024) >> 7) * 64;
  const int n0 = isqk ? (bid & 7) * 64 : ((bid - 1024) & 127) * 64;
  const int t = threadIdx.x;
  {
    const int row = t >> 2, cb = (t & 3) * 64;
    const u16* ga = A  + (size_t)(m0 + row) * 256 + cb;
    const u16* gb = Bt + (size_t)(n0 + row) * 256 + cb;
#pragma unroll
    for (int i = 0; i < 8; ++i) {
      *(int4*)&At[row][cb + i * 8] = *(const int4*)(ga + i * 8);
      *(int4*)&Bs[row][cb + i * 8] = *(const int4*)(gb + i * 8);
    }
  }
  __syncthreads();
  const int w = t >> 6, l = t & 63, g = l >> 4, c = l & 15;
  f32x4 acc[4] = {};
#pragma unroll
  for (int kk = 0; kk < 256; kk += 32) {
    bf16x8 af = *(const bf16x8*)&At[w * 16 + c][kk + g * 8];
#pragma unroll
    for (int j = 0; j < 4; ++j) {
      bf16x8 bfr = *(const bf16x8*)&Bs[j * 16 + c][kk + g * 8];
      acc[j] = __builtin_amdgcn_mfma_f32_16x16x32_bf16(af, bfr, acc[j], 0, 0, 0);
    }
  }
  if (isqk) {
    if (n0 < 256) {
#pragma unroll
      for (int j = 0; j < 4; ++j)
#pragma unroll
        for (int r = 0; r < 4; ++r) {
          int m = m0 + w * 16 + g * 4 + r, n = n0 + j * 16 + c;
          qout[(size_t)m * 256 + n] = bfu((acc[j][r] + bqkv[n]) * LAMBDA);
        }
    } else {
#pragma unroll
      for (int j = 0; j < 4; ++j)
#pragma unroll
        for (int r = 0; r < 4; ++r) {
          int m = m0 + w * 16 + g * 4 + r, n = n0 + j * 16 + c;
          int ch = n - 256;
          kout[(size_t)((m >> 11) * 8 + (ch >> 5)) * 65536 + (size_t)(m & 2047) * 32 + (ch & 31)]
              = bfu(acc[j][r] + bqkv[n]);
        }
    }
  } else {
#pragma unroll
    for (int j = 0; j < 4; ++j)
#pragma unroll
      for (int r = 0; r < 4; ++r) {
        int m = m0 + w * 16 + g * 4 + r;   // channel
        int n = n0 + j * 16 + c;           // token
        vtout[(size_t)m * 8192 + n] = bfu(acc[j][r] + bqkv[512 + m]);
      }
  }
}

// ---------------- fused sigmoid-gated attention ----------------
// = round-9 PASSING build with ONE change: sigmoid via bare v_exp (exp2) --
//   q pre-scaled by -log2e/sqrt(32), so p = mf * rcp(1 + exp2(s)); removes the
//   4 v_mul(log2e) per tt that __expf needed. Range-safe: exp2->inf => p=0 exact.
__global__ __launch_bounds__(256) void attn_kernel(
    const u16* __restrict__ qb,            // [8192][256] bf16, LAMBDA-scaled
    const u16* __restrict__ kb,            // [B][H][2048][32] bf16
    const u16* __restrict__ vtb,           // [256][8192] bf16 (V^T)
    const unsigned char* __restrict__ m8,  // [2048][2048] 0/1
    u16* __restrict__ ob) {                // [8192][256] bf16
  __shared__ u32 Klds[2][64][20];          // 16 data u32 + 4 pad (row 80 B)
  __shared__ u32 Vlds[2][32][36];          // 32 data u32 + 4 pad (row 144 B)
  __shared__ unsigned char Mlds[2][64][64];// mask tile, byte-rotated rows
  __shared__ u32 Plds[4][16][36];          // 32 data u32 + 4 pad, per-wave

  const int bid = blockIdx.x;
  const int qt = bid & 31, h = (bid >> 5) & 7, b = bid >> 8;
  const int q0 = qt * 64;
  const int t = threadIdx.x, w = t >> 6, l = t & 63, g = l >> 4, c = l & 15;

  const bf16x8 qf = asfrag(*(const uint4*)(qb + (size_t)(b * NN + q0 + 16 * w + c) * 256 + h * 32 + 8 * g));
  f32x4 oacc[2] = {};

  const int srowK = t >> 2, ssegK = t & 3;
  const int srowV = t >> 3, ssegV = t & 7;
  const u16* kg = kb + (size_t)(b * 8 + h) * 65536 + srowK * 32 + ssegK * 8;
  const u16* vg = vtb + (size_t)(h * 32 + srowV) * 8192 + (size_t)b * NN + ssegV * 8;
  const unsigned char* mg = m8 + (size_t)(q0 + srowK) * NN + ssegK * 16;

  const int mb0 = (16 * ssegK + 8 * (srowK & 7)) & 63;
  const int mb1 = (mb0 + 8) & 63;

  uint4 krg = *(const uint4*)kg;
  uint4 vrg = *(const uint4*)vg;
  uint4 mrg = *(const uint4*)mg;
  *(uint4*)&Klds[0][srowK][ssegK * 4] = krg;
  *(uint4*)&Vlds[0][srowV][ssegV * 4] = vrg;
  *(uint2*)&Mlds[0][srowK][mb0] = make_uint2(mrg.x, mrg.y);
  *(uint2*)&Mlds[0][srowK][mb1] = make_uint2(mrg.z, mrg.w);
  __syncthreads();

  const f32x4 zf = {0.f, 0.f, 0.f, 0.f};
  u32* Pw = &Plds[w][0][0];

  for (int it = 0; it < 32; ++it) {
    const int cur = it & 1;
    if (it < 31) {
      const int kt = (it + 1) * 64;
      krg = *(const uint4*)(kg + (size_t)kt * 32);
      vrg = *(const uint4*)(vg + kt);
      mrg = *(const uint4*)(mg + kt);
    }
#pragma unroll
    for (int tt = 0; tt < 4; ++tt) {
      bf16x8 kf = asfrag(*(const uint4*)&Klds[cur][16 * tt + c][4 * g]);
      f32x4 s = __builtin_amdgcn_mfma_f32_16x16x32_bf16(kf, qf, zf, 0, 0, 0);
      u32 mdw = *(const u32*)&Mlds[cur][16 * w + c][(16 * tt + 4 * g + 8 * (c & 7)) & 63];
      float mf0 = (float)(mdw & 0xffu);
      float mf1 = (float)((mdw >> 8) & 0xffu);
      float mf2 = (float)((mdw >> 16) & 0xffu);
      float mf3 = (float)(mdw >> 24);
      float p0 = mf0 * __builtin_amdgcn_rcpf(1.f + __builtin_amdgcn_exp2f(s[0]));
      float p1 = mf1 * __builtin_amdgcn_rcpf(1.f + __builtin_amdgcn_exp2f(s[1]));
      float p2 = mf2 * __builtin_amdgcn_rcpf(1.f + __builtin_amdgcn_exp2f(s[2]));
      float p3 = mf3 * __builtin_amdgcn_rcpf(1.f + __builtin_amdgcn_exp2f(s[3]));
      u32 w0, w1;
      asm("v_cvt_pk_bf16_f32 %0, %1, %2" : "=v"(w0) : "v"(p0), "v"(p1));
      asm("v_cvt_pk_bf16_f32 %0, %1, %2" : "=v"(w1) : "v"(p2), "v"(p3));
      *(uint2*)&Pw[c * 36 + 8 * tt + 2 * g] = make_uint2(w0, w1);
    }
    asm volatile("s_waitcnt lgkmcnt(0)" ::: "memory");
    __builtin_amdgcn_sched_barrier(0);
#pragma unroll
    for (int kk = 0; kk < 2; ++kk) {
      bf16x8 pf = asfrag(*(const uint4*)&Pw[c * 36 + 16 * kk + 4 * g]);
#pragma unroll
      for (int d0 = 0; d0 < 2; ++d0) {
        bf16x8 vf = asfrag(*(const uint4*)&Vlds[cur][16 * d0 + c][16 * kk + 4 * g]);
        oacc[d0] = __builtin_amdgcn_mfma_f32_16x16x32_bf16(pf, vf, oacc[d0], 0, 0, 0);
      }
    }
    if (it < 31) {
      *(uint4*)&Klds[cur ^ 1][srowK][ssegK * 4] = krg;
      *(uint4*)&Vlds[cur ^ 1][srowV][ssegV * 4] = vrg;
      *(uint2*)&Mlds[cur ^ 1][srowK][mb0] = make_uint2(mrg.x, mrg.y);
      *(uint2*)&Mlds[cur ^ 1][srowK][mb1] = make_uint2(mrg.z, mrg.w);
    }
    __syncthreads();
  }

  const size_t obase = (size_t)(b * NN + q0 + 16 * w) * 256 + h * 32;
#pragma unroll
  for (int d0 = 0; d0 < 2; ++d0)
#pragma unroll
    for (int r = 0; r < 4; ++r)
      ob[obase + (size_t)(4 * g + r) * 256 + 16 * d0 + c] = bfu(oacc[d0][r]);
}

// ---------------- fused tail: Wo+res -> LN1 -> FF1+relu -> FF2+res -> LN2 ----------------
// 512 blocks x 4 waves; block = 16 rows, wave w = cols [64w,64w+64).
__global__ __launch_bounds__(256) void tail_kernel(
    const u16* __restrict__ obuf, const u16* __restrict__ woT,
    const u16* __restrict__ w1T, const u16* __restrict__ w2T,
    const float* __restrict__ xp,          // [8192][256] f32, permuted [row][c*16+j16]
    const float* __restrict__ bo, const float* __restrict__ b1, const float* __restrict__ b2,
    const float* __restrict__ g1, const float* __restrict__ be1,
    const float* __restrict__ g2, const float* __restrict__ be2,
    float* __restrict__ out) {
  __shared__ u16 A[16][264];               // bf16 activation tile
  __shared__ float T1[16][260];            // f32 LN1-output / scratch z
  __shared__ float PS1[16][4], PS2[16][4]; // cross-wave LN partials
  const int t = threadIdx.x, w = t >> 6, l = t & 63, g = l >> 4, c = l & 15;
  const int m0 = blockIdx.x * 16;          // block's 16 rows
  const int n0 = w * 64;                   // wave's 64 cols
  const f32x4 zf4 = {0.f, 0.f, 0.f, 0.f};

  // ---- stage obuf rows m0..m0+15 (256 threads, 2 x 16B each) ----
  {
    const int srow = t >> 4, sseg = t & 15;
#pragma unroll
    for (int i = 0; i < 2; ++i) {
      uint4 v = *(const uint4*)(obuf + (size_t)(m0 + srow) * 256 + (sseg + 16 * i) * 8);
      *(uint4*)&A[srow][(sseg + 16 * i) * 8] = v;
    }
  }
  __syncthreads();

  f32x4 acc[4];
  float mean[4], inv[4];

  // ---- GEMM1: obuf @ Wo (wave's 64 cols) ----
#pragma unroll
  for (int j = 0; j < 4; ++j) acc[j] = zf4;
#pragma unroll
  for (int kk = 0; kk < 256; kk += 32) {
    bf16x8 af = *(const bf16x8*)&A[c][kk + 8 * g];
#pragma unroll
    for (int j = 0; j < 4; ++j) {
      bf16x8 bfr = asfrag(*(const uint4*)(woT + (size_t)(n0 + 16 * j + c) * 256 + kk + 8 * g));
      acc[j] = __builtin_amdgcn_mfma_f32_16x16x32_bf16(af, bfr, acc[j], 0, 0, 0);
    }
  }
  // ---- epilogue1: z = acc + bo + x -> T1, wave partial stats -> PS ----
  {
    float bov[4];
#pragma unroll
    for (int j = 0; j < 4; ++j) bov[j] = bo[n0 + 16 * j + c];
#pragma unroll
    for (int r = 0; r < 4; ++r) {
      float4 xq = ((const float4*)(xp + (size_t)(m0 + 4 * g + r) * 256 + c * 16))[w];
      float xa[4] = {xq.x, xq.y, xq.z, xq.w};
      float a1 = 0.f, a2 = 0.f;
#pragma unroll
      for (int j = 0; j < 4; ++j) {
        float z = acc[j][r] + bov[j] + xa[j];
        T1[4 * g + r][n0 + 16 * j + c] = z;
        a1 += z; a2 += z * z;
      }
#pragma unroll
      for (int off = 1; off < 16; off <<= 1) {
        a1 += __shfl_xor(a1, off);
        a2 += __shfl_xor(a2, off);
      }
      if (c == 0) { PS1[4 * g + r][w] = a1; PS2[4 * g + r][w] = a2; }
    }
  }
  __syncthreads();
#pragma unroll
  for (int r = 0; r < 4; ++r) {
    const int row = 4 * g + r;
    float s1 = PS1[row][0] + PS1[row][1] + PS1[row][2] + PS1[row][3];
    float s2 = PS2[row][0] + PS2[row][1] + PS2[row][2] + PS2[row][3];
    mean[r] = s1 * (1.f / 256.f);
    inv[r] = rsqrtf(s2 * (1.f / 256.f) - mean[r] * mean[r] + 1e-5f);
  }
  // normalize T1 in place (LN1 out, kept for FF2 residual) + bf16 tile -> A
#pragma unroll
  for (int j = 0; j < 4; ++j) {
    const int n = n0 + 16 * j + c;
    const float gv = g1[n], bev = be1[n];
#pragma unroll
    for (int r = 0; r < 4; ++r) {
      float v = (T1[4 * g + r][n] - mean[r]) * inv[r] * gv + bev;
      T1[4 * g + r][n] = v;
      A[4 * g + r][n] = bfu(v);
    }
  }
  __syncthreads();

  // ---- GEMM2: t1 @ W1, relu ----
#pragma unroll
  for (int j = 0; j < 4; ++j) acc[j] = zf4;
#pragma unroll
  for (int kk = 0; kk < 256; kk += 32) {
    bf16x8 af = *(const bf16x8*)&A[c][kk + 8 * g];
#pragma unroll
    for (int j = 0; j < 4; ++j) {
      bf16x8 bfr = asfrag(*(const uint4*)(w1T + (size_t)(n0 + 16 * j + c) * 256 + kk + 8 * g));
      acc[j] = __builtin_amdgcn_mfma_f32_16x16x32_bf16(af, bfr, acc[j], 0, 0, 0);
    }
  }
  __syncthreads();                         // all waves done reading A
#pragma unroll
  for (int j = 0; j < 4; ++j) {
    const int n = n0 + 16 * j + c;
    const float bv = b1[n];
#pragma unroll
    for (int r = 0; r < 4; ++r) {
      float v = acc[j][r] + bv;
      A[4 * g + r][n] = bfu(v > 0.f ? v : 0.f);
    }
  }
  __syncthreads();

  // ---- GEMM3: h @ W2 ----
#pragma unroll
  for (int j = 0; j < 4; ++j) acc[j] = zf4;
#pragma unroll
  for (int kk = 0; kk < 256; kk += 32) {
    bf16x8 af = *(const bf16x8*)&A[c][kk + 8 * g];
#pragma unroll
    for (int j = 0; j < 4; ++j) {
      bf16x8 bfr = asfrag(*(const uint4*)(w2T + (size_t)(n0 + 16 * j + c) * 256 + kk + 8 * g));
      acc[j] = __builtin_amdgcn_mfma_f32_16x16x32_bf16(af, bfr, acc[j], 0, 0, 0);
    }
  }
  // ---- epilogue3: z = acc + b2 + t1; LN2 -> out ----
  {
    float b2v[4];
#pragma unroll
    for (int j = 0; j < 4; ++j) b2v[j] = b2[n0 + 16 * j + c];
#pragma unroll
    for (int r = 0; r < 4; ++r) {
      float a1 = 0.f, a2 = 0.f;
#pragma unroll
      for (int j = 0; j < 4; ++j) {
        const int n = n0 + 16 * j + c;
        float z = acc[j][r] + b2v[j] + T1[4 * g + r][n];
        T1[4 * g + r][n] = z;
        a1 += z; a2 += z * z;
      }
#pragma unroll
      for (int off = 1; off < 16; off <<= 1) {
        a1 += __shfl_xor(a1, off);
        a2 += __shfl_xor(a2, off);
      }
      if (c == 0) { PS1[4 * g + r][w] = a1; PS2[4 * g + r][w] = a2; }
    }
  }
  __syncthreads();
#pragma unroll
  for (int r = 0; r < 4; ++r) {
    const int row = 4 * g + r;
    float s1 = PS1[row][0] + PS1[row][1] + PS1[row][2] + PS1[row][3];
    float s2 = PS2[row][0] + PS2[row][1] + PS2[row][2] + PS2[row][3];
    mean[r] = s1 * (1.f / 256.f);
    inv[r] = rsqrtf(s2 * (1.f / 256.f) - mean[r] * mean[r] + 1e-5f);
  }
#pragma unroll
  for (int j = 0; j < 4; ++j) {
    const int n = n0 + 16 * j + c;
    const float gv = g2[n], bev = be2[n];
#pragma unroll
    for (int r = 0; r < 4; ++r)
      out[(size_t)(m0 + 4 * g + r) * 256 + n] = (T1[4 * g + r][n] - mean[r]) * inv[r] * gv + bev;
  }
}

extern "C" void kernel_launch(void* const* d_in, const int* in_sizes, int n_in,
                              void* d_out, int out_size, void* d_ws, size_t ws_size,
                              hipStream_t stream) {
  const float* qdt   = (const float*)d_in[0];
  const float* boxes = (const float*)d_in[1];
  const int*   mask  = (const int*)d_in[2];
  const float* Wq = (const float*)d_in[3];
  const float* bq = (const float*)d_in[4];
  const float* Wk = (const float*)d_in[5];
  const float* bk = (const float*)d_in[6];
  const float* Wv = (const float*)d_in[7];
  const float* bv = (const float*)d_in[8];
  const float* Wo = (const float*)d_in[9];
  const float* bo = (const float*)d_in[10];
  const float* W1 = (const float*)d_in[11];
  const float* b1 = (const float*)d_in[12];
  const float* W2 = (const float*)d_in[13];
  const float* b2 = (const float*)d_in[14];
  const float* g1  = (const float*)d_in[15];
  const float* be1 = (const float*)d_in[16];
  const float* g2  = (const float*)d_in[17];
  const float* be2 = (const float*)d_in[18];

  char* ws = (char*)d_ws;
  float* xp    = (float*)(ws + 0);          // [8192,256] f32 permuted residual
  u16*   xb    = (u16*)  (ws + 8388608);
  u16*   qbuf  = (u16*)  (ws + 12582912);   // q, LAMBDA-scaled
  u16*   kbuf  = (u16*)  (ws + 16777216);   // [B][H][2048][32]
  u16*   vtbuf = (u16*)  (ws + 20971520);   // [256][8192]
  u16*   obuf  = (u16*)  (ws + 25165824);
  u16*   wqkvT = (u16*)  (ws + 46137344);   // [768,256]
  u16*   woT   = (u16*)  (ws + 46530560);
  u16*   w1T   = (u16*)  (ws + 46661632);
  u16*   w2T   = (u16*)  (ws + 46792704);
  float* bqkv  = (float*)(ws + 46923776);
  unsigned char* m8 = (unsigned char*)(ws + 46926848);  // [2048,2048] u8

  // merged prep: xp/xb (2048 blk) + mask->m8 (4096 blk) + weights (1539 blk)
  prep_kernel<<<7683, 256, 0, stream>>>(qdt, boxes, mask, Wq, Wk, Wv, Wo, W1, W2,
                                        bq, bk, bv, xp, xb, m8,
                                        wqkvT, woT, w1T, w2T, bqkv);
  // fused Q(scaled)/K(relayout) + V^T: 1024 + 512 blocks
  gemm_qkvt_kernel<<<1536, 256, 0, stream>>>(xb, wqkvT, bqkv, qbuf, kbuf, vtbuf);
  // attention
  attn_kernel<<<1024, 256, 0, stream>>>(qbuf, kbuf, vtbuf, m8, obuf);
  // fused tail: Wo+res -> LN1 -> FF1+relu -> FF2+res -> LN2 -> d_out
  tail_kernel<<<512, 256, 0, stream>>>(obuf, woT, w1T, w2T, xp,
                                       bo, b1, b2, g1, be1, g2, be2, (float*)d_out);
}

// Round 13
// 112.298 us; speedup vs baseline: 1.6938x; 1.0057x over previous
//
#include <hip/hip_runtime.h>
#include <hip/hip_bf16.h>

typedef unsigned short u16;
typedef unsigned int u32;
typedef __attribute__((ext_vector_type(8))) short bf16x8;   // 8 bf16 (MFMA x32 A/B frag)
typedef __attribute__((ext_vector_type(4))) float f32x4;    // MFMA C/D frag

#define BB 4
#define NN 2048
#define DD 256
#define HH 8
#define LAMBDA (-0.2550351f)  // -log2(e)/sqrt(32): folded into Q so sigmoid = rcp(1+exp2(s))

__device__ inline u16 bfu(float f) {
  __hip_bfloat16 h = __float2bfloat16(f);
  return *reinterpret_cast<u16*>(&h);
}
__device__ inline bf16x8 asfrag(uint4 v) { return __builtin_bit_cast(bf16x8, v); }

// ---------------- merged prep: x(permuted)+xb, mask->u8, weights ----------------
__global__ __launch_bounds__(256) void prep_kernel(
    const float* __restrict__ qdt, const float* __restrict__ boxes,
    const int* __restrict__ mask,
    const float* __restrict__ Wq, const float* __restrict__ Wk, const float* __restrict__ Wv,
    const float* __restrict__ Wo, const float* __restrict__ W1, const float* __restrict__ W2,
    const float* __restrict__ bq, const float* __restrict__ bk, const float* __restrict__ bv,
    float* __restrict__ xp, u16* __restrict__ xb, unsigned char* __restrict__ m8,
    u16* __restrict__ wqkvT, u16* __restrict__ woT, u16* __restrict__ w1T, u16* __restrict__ w2T,
    float* __restrict__ bqkv) {
  const int bid = blockIdx.x, t = threadIdx.x;
  if (bid < 2048) {                       // x = qdt + boxes (permuted fp32 + linear bf16)
    int i = bid * 256 + t;
    int row = i >> 6, q = i & 63;
    float4 a = ((const float4*)qdt)[i];
    float4 b = ((const float4*)boxes)[i];
    float4 v = make_float4(a.x + b.x, a.y + b.y, a.z + b.z, a.w + b.w);
    ((ushort4*)xb)[i] = make_ushort4(bfu(v.x), bfu(v.y), bfu(v.z), bfu(v.w));
    float* xr = xp + (size_t)row * 256;
    xr[((4*q+0) & 15) * 16 + ((4*q+0) >> 4)] = v.x;
    xr[((4*q+1) & 15) * 16 + ((4*q+1) >> 4)] = v.y;
    xr[((4*q+2) & 15) * 16 + ((4*q+2) >> 4)] = v.z;
    xr[((4*q+3) & 15) * 16 + ((4*q+3) >> 4)] = v.w;
  } else if (bid < 6144) {                // mask int -> u8 0/1
    int i = (bid - 2048) * 256 + t;
    int4 m = ((const int4*)mask)[i];
    ((uchar4*)m8)[i] = make_uchar4((unsigned char)m.x, (unsigned char)m.y,
                                   (unsigned char)m.z, (unsigned char)m.w);
  } else {                                // weight transposes + qkv bias concat
    int i = (bid - 6144) * 256 + t;
    if (i < 196608) {
      int n = i >> 8, k = i & 255;
      const float* src = (n < 256) ? Wq : (n < 512 ? Wk : Wv);
      wqkvT[i] = bfu(src[k * 256 + (n & 255)]);
    } else if (i < 262144) {
      int j = i - 196608; int n = j >> 8, k = j & 255;
      woT[j] = bfu(Wo[k * 256 + n]);
    } else if (i < 327680) {
      int j = i - 262144; int n = j >> 8, k = j & 255;
      w1T[j] = bfu(W1[k * 256 + n]);
    } else if (i < 393216) {
      int j = i - 327680; int n = j >> 8, k = j & 255;
      w2T[j] = bfu(W2[k * 256 + n]);
    } else if (i < 393984) {
      int n = i - 393216;
      bqkv[n] = (n < 256) ? bq[n] : (n < 512 ? bk[n - 256] : bv[n - 512]);
    }
  }
}

// ---------------- fused QKV-side GEMM: Q(scaled)+K(relayout) and V^T in one launch -------
__global__ __launch_bounds__(256) void gemm_qkvt_kernel(
    const u16* __restrict__ xb, const u16* __restrict__ wqkvT,
    const float* __restrict__ bqkv,
    u16* __restrict__ qout, u16* __restrict__ kout, u16* __restrict__ vtout) {
  __shared__ u16 At[64][264];
  __shared__ u16 Bs[64][264];
  const int bid = blockIdx.x;
  const bool isqk = bid < 1024;
  const u16* A  = isqk ? xb : (wqkvT + 512 * 256);
  const u16* Bt = isqk ? wqkvT : xb;
  const int m0 = isqk ? (bid >> 3) * 64 : ((bid - 1024) >> 7) * 64;
  const int n0 = isqk ? (bid & 7) * 64 : ((bid - 1024) & 127) * 64;
  const int t = threadIdx.x;
  {
    const int row = t >> 2, cb = (t & 3) * 64;
    const u16* ga = A  + (size_t)(m0 + row) * 256 + cb;
    const u16* gb = Bt + (size_t)(n0 + row) * 256 + cb;
#pragma unroll
    for (int i = 0; i < 8; ++i) {
      *(int4*)&At[row][cb + i * 8] = *(const int4*)(ga + i * 8);
      *(int4*)&Bs[row][cb + i * 8] = *(const int4*)(gb + i * 8);
    }
  }
  __syncthreads();
  const int w = t >> 6, l = t & 63, g = l >> 4, c = l & 15;
  f32x4 acc[4] = {};
#pragma unroll
  for (int kk = 0; kk < 256; kk += 32) {
    bf16x8 af = *(const bf16x8*)&At[w * 16 + c][kk + g * 8];
#pragma unroll
    for (int j = 0; j < 4; ++j) {
      bf16x8 bfr = *(const bf16x8*)&Bs[j * 16 + c][kk + g * 8];
      acc[j] = __builtin_amdgcn_mfma_f32_16x16x32_bf16(af, bfr, acc[j], 0, 0, 0);
    }
  }
  if (isqk) {
    if (n0 < 256) {
#pragma unroll
      for (int j = 0; j < 4; ++j)
#pragma unroll
        for (int r = 0; r < 4; ++r) {
          int m = m0 + w * 16 + g * 4 + r, n = n0 + j * 16 + c;
          qout[(size_t)m * 256 + n] = bfu((acc[j][r] + bqkv[n]) * LAMBDA);
        }
    } else {
#pragma unroll
      for (int j = 0; j < 4; ++j)
#pragma unroll
        for (int r = 0; r < 4; ++r) {
          int m = m0 + w * 16 + g * 4 + r, n = n0 + j * 16 + c;
          int ch = n - 256;
          kout[(size_t)((m >> 11) * 8 + (ch >> 5)) * 65536 + (size_t)(m & 2047) * 32 + (ch & 31)]
              = bfu(acc[j][r] + bqkv[n]);
        }
    }
  } else {
#pragma unroll
    for (int j = 0; j < 4; ++j)
#pragma unroll
      for (int r = 0; r < 4; ++r) {
        int m = m0 + w * 16 + g * 4 + r;   // channel
        int n = n0 + j * 16 + c;           // token
        vtout[(size_t)m * 8192 + n] = bfu(acc[j][r] + bqkv[512 + m]);
      }
  }
}

// ---------------- fused sigmoid-gated attention (round-11 PASSING build, reverted) -------
// PV-in-regs via mfma_16x16x16bf16_1k produced NaN (unverified gfx950 builtin) -> back to
// the proven Plds round-trip with the rule-18 hard fence.
__global__ __launch_bounds__(256) void attn_kernel(
    const u16* __restrict__ qb,            // [8192][256] bf16, LAMBDA-scaled
    const u16* __restrict__ kb,            // [B][H][2048][32] bf16
    const u16* __restrict__ vtb,           // [256][8192] bf16 (V^T)
    const unsigned char* __restrict__ m8,  // [2048][2048] 0/1
    u16* __restrict__ ob) {                // [8192][256] bf16
  __shared__ u32 Klds[2][64][20];          // 16 data u32 + 4 pad (row 80 B)
  __shared__ u32 Vlds[2][32][36];          // 32 data u32 + 4 pad (row 144 B)
  __shared__ unsigned char Mlds[2][64][64];// mask tile, byte-rotated rows
  __shared__ u32 Plds[4][16][36];          // 32 data u32 + 4 pad, per-wave

  const int bid = blockIdx.x;
  const int qt = bid & 31, h = (bid >> 5) & 7, b = bid >> 8;
  const int q0 = qt * 64;
  const int t = threadIdx.x, w = t >> 6, l = t & 63, g = l >> 4, c = l & 15;

  const bf16x8 qf = asfrag(*(const uint4*)(qb + (size_t)(b * NN + q0 + 16 * w + c) * 256 + h * 32 + 8 * g));
  f32x4 oacc[2] = {};

  const int srowK = t >> 2, ssegK = t & 3;
  const int srowV = t >> 3, ssegV = t & 7;
  const u16* kg = kb + (size_t)(b * 8 + h) * 65536 + srowK * 32 + ssegK * 8;
  const u16* vg = vtb + (size_t)(h * 32 + srowV) * 8192 + (size_t)b * NN + ssegV * 8;
  const unsigned char* mg = m8 + (size_t)(q0 + srowK) * NN + ssegK * 16;

  const int mb0 = (16 * ssegK + 8 * (srowK & 7)) & 63;
  const int mb1 = (mb0 + 8) & 63;

  uint4 krg = *(const uint4*)kg;
  uint4 vrg = *(const uint4*)vg;
  uint4 mrg = *(const uint4*)mg;
  *(uint4*)&Klds[0][srowK][ssegK * 4] = krg;
  *(uint4*)&Vlds[0][srowV][ssegV * 4] = vrg;
  *(uint2*)&Mlds[0][srowK][mb0] = make_uint2(mrg.x, mrg.y);
  *(uint2*)&Mlds[0][srowK][mb1] = make_uint2(mrg.z, mrg.w);
  __syncthreads();

  const f32x4 zf = {0.f, 0.f, 0.f, 0.f};
  u32* Pw = &Plds[w][0][0];

  for (int it = 0; it < 32; ++it) {
    const int cur = it & 1;
    if (it < 31) {
      const int kt = (it + 1) * 64;
      krg = *(const uint4*)(kg + (size_t)kt * 32);
      vrg = *(const uint4*)(vg + kt);
      mrg = *(const uint4*)(mg + kt);
    }
#pragma unroll
    for (int tt = 0; tt < 4; ++tt) {
      bf16x8 kf = asfrag(*(const uint4*)&Klds[cur][16 * tt + c][4 * g]);
      f32x4 s = __builtin_amdgcn_mfma_f32_16x16x32_bf16(kf, qf, zf, 0, 0, 0);
      u32 mdw = *(const u32*)&Mlds[cur][16 * w + c][(16 * tt + 4 * g + 8 * (c & 7)) & 63];
      float mf0 = (float)(mdw & 0xffu);
      float mf1 = (float)((mdw >> 8) & 0xffu);
      float mf2 = (float)((mdw >> 16) & 0xffu);
      float mf3 = (float)(mdw >> 24);
      float p0 = mf0 * __builtin_amdgcn_rcpf(1.f + __builtin_amdgcn_exp2f(s[0]));
      float p1 = mf1 * __builtin_amdgcn_rcpf(1.f + __builtin_amdgcn_exp2f(s[1]));
      float p2 = mf2 * __builtin_amdgcn_rcpf(1.f + __builtin_amdgcn_exp2f(s[2]));
      float p3 = mf3 * __builtin_amdgcn_rcpf(1.f + __builtin_amdgcn_exp2f(s[3]));
      u32 w0, w1;
      asm("v_cvt_pk_bf16_f32 %0, %1, %2" : "=v"(w0) : "v"(p0), "v"(p1));
      asm("v_cvt_pk_bf16_f32 %0, %1, %2" : "=v"(w1) : "v"(p2), "v"(p3));
      *(uint2*)&Pw[c * 36 + 8 * tt + 2 * g] = make_uint2(w0, w1);
    }
    asm volatile("s_waitcnt lgkmcnt(0)" ::: "memory");
    __builtin_amdgcn_sched_barrier(0);
#pragma unroll
    for (int kk = 0; kk < 2; ++kk) {
      bf16x8 pf = asfrag(*(const uint4*)&Pw[c * 36 + 16 * kk + 4 * g]);
#pragma unroll
      for (int d0 = 0; d0 < 2; ++d0) {
        bf16x8 vf = asfrag(*(const uint4*)&Vlds[cur][16 * d0 + c][16 * kk + 4 * g]);
        oacc[d0] = __builtin_amdgcn_mfma_f32_16x16x32_bf16(pf, vf, oacc[d0], 0, 0, 0);
      }
    }
    if (it < 31) {
      *(uint4*)&Klds[cur ^ 1][srowK][ssegK * 4] = krg;
      *(uint4*)&Vlds[cur ^ 1][srowV][ssegV * 4] = vrg;
      *(uint2*)&Mlds[cur ^ 1][srowK][mb0] = make_uint2(mrg.x, mrg.y);
      *(uint2*)&Mlds[cur ^ 1][srowK][mb1] = make_uint2(mrg.z, mrg.w);
    }
    __syncthreads();
  }

  const size_t obase = (size_t)(b * NN + q0 + 16 * w) * 256 + h * 32;
#pragma unroll
  for (int d0 = 0; d0 < 2; ++d0)
#pragma unroll
    for (int r = 0; r < 4; ++r)
      ob[obase + (size_t)(4 * g + r) * 256 + 16 * d0 + c] = bfu(oacc[d0][r]);
}

// ---------------- fused tail v3: Wo+res -> LN1 -> FF1+relu -> FF2+res -> LN2 -------------
// 256 blocks x 4 waves; block = 32 rows, wave = 32 rows x 64 cols (rg in {0,1}).
// Per kk-step: 2 A-reads + 4 B-reads + 8 MFMA (2x density of r10's tail).
// t1 (LN1 out / FF2 residual) in 32 VGPRs -- GEMM3's acc[rg][j][r] has the SAME
// (row,col) mapping as epilogue1's z, so no full-width residual storage needed.
__global__ __launch_bounds__(256) void tail_kernel(
    const u16* __restrict__ obuf, const u16* __restrict__ woT,
    const u16* __restrict__ w1T, const u16* __restrict__ w2T,
    const float* __restrict__ xp,          // [8192][256] f32, permuted [row][c*16+4w+j]
    const float* __restrict__ bo, const float* __restrict__ b1, const float* __restrict__ b2,
    const float* __restrict__ g1, const float* __restrict__ be1,
    const float* __restrict__ g2, const float* __restrict__ be2,
    float* __restrict__ out) {
  __shared__ u16 A[32][264];               // bf16 activation tile
  __shared__ float PS1[32][4], PS2[32][4]; // cross-wave LN partials
  const int t = threadIdx.x, w = t >> 6, l = t & 63, g = l >> 4, c = l & 15;
  const int m0 = blockIdx.x * 32;          // block's 32 rows
  const int n0 = w * 64;                   // wave's 64 cols
  const f32x4 zf4 = {0.f, 0.f, 0.f, 0.f};

  // ---- stage obuf rows m0..m0+31 (256 threads, 4 x 16B each) ----
  {
    const int srow = t >> 3, sseg = t & 7;
#pragma unroll
    for (int i = 0; i < 4; ++i) {
      uint4 v = *(const uint4*)(obuf + (size_t)(m0 + srow) * 256 + (sseg + 8 * i) * 8);
      *(uint4*)&A[srow][(sseg + 8 * i) * 8] = v;
    }
  }
  __syncthreads();

  f32x4 acc[2][4], t1[2][4];
  float mean[2][4], inv[2][4];

  // ---- GEMM1: obuf @ Wo ----
#pragma unroll
  for (int rg = 0; rg < 2; ++rg)
#pragma unroll
    for (int j = 0; j < 4; ++j) acc[rg][j] = zf4;
#pragma unroll
  for (int kk = 0; kk < 256; kk += 32) {
    bf16x8 af0 = *(const bf16x8*)&A[c][kk + 8 * g];
    bf16x8 af1 = *(const bf16x8*)&A[16 + c][kk + 8 * g];
#pragma unroll
    for (int j = 0; j < 4; ++j) {
      bf16x8 bfr = asfrag(*(const uint4*)(woT + (size_t)(n0 + 16 * j + c) * 256 + kk + 8 * g));
      acc[0][j] = __builtin_amdgcn_mfma_f32_16x16x32_bf16(af0, bfr, acc[0][j], 0, 0, 0);
      acc[1][j] = __builtin_amdgcn_mfma_f32_16x16x32_bf16(af1, bfr, acc[1][j], 0, 0, 0);
    }
  }
  // ---- epilogue1: z = acc + bo + x -> t1 regs; LN1 partials -> PS ----
  {
    float bov[4];
#pragma unroll
    for (int j = 0; j < 4; ++j) bov[j] = bo[n0 + 16 * j + c];
#pragma unroll
    for (int rg = 0; rg < 2; ++rg)
#pragma unroll
      for (int r = 0; r < 4; ++r) {
        const int rl = 16 * rg + 4 * g + r;
        float4 xq = ((const float4*)(xp + (size_t)(m0 + rl) * 256 + c * 16))[w];
        float xa[4] = {xq.x, xq.y, xq.z, xq.w};
        float a1 = 0.f, a2 = 0.f;
#pragma unroll
        for (int j = 0; j < 4; ++j) {
          float z = acc[rg][j][r] + bov[j] + xa[j];
          t1[rg][j][r] = z;
          a1 += z; a2 += z * z;
        }
#pragma unroll
        for (int off = 1; off < 16; off <<= 1) {
          a1 += __shfl_xor(a1, off);
          a2 += __shfl_xor(a2, off);
        }
        if (c == 0) { PS1[rl][w] = a1; PS2[rl][w] = a2; }
      }
  }
  __syncthreads();
#pragma unroll
  for (int rg = 0; rg < 2; ++rg)
#pragma unroll
    for (int r = 0; r < 4; ++r) {
      const int rl = 16 * rg + 4 * g + r;
      float s1 = PS1[rl][0] + PS1[rl][1] + PS1[rl][2] + PS1[rl][3];
      float s2 = PS2[rl][0] + PS2[rl][1] + PS2[rl][2] + PS2[rl][3];
      mean[rg][r] = s1 * (1.f / 256.f);
      inv[rg][r] = rsqrtf(s2 * (1.f / 256.f) - mean[rg][r] * mean[rg][r] + 1e-5f);
    }
  // normalize into t1 regs (kept for FF2 residual) + bf16 tile -> A
#pragma unroll
  for (int j = 0; j < 4; ++j) {
    const int n = n0 + 16 * j + c;
    const float gv = g1[n], bev = be1[n];
#pragma unroll
    for (int rg = 0; rg < 2; ++rg)
#pragma unroll
      for (int r = 0; r < 4; ++r) {
        float v = (t1[rg][j][r] - mean[rg][r]) * inv[rg][r] * gv + bev;
        t1[rg][j][r] = v;
        A[16 * rg + 4 * g + r][n] = bfu(v);
      }
  }
  __syncthreads();

  // ---- GEMM2: t1 @ W1, relu ----
#pragma unroll
  for (int rg = 0; rg < 2; ++rg)
#pragma unroll
    for (int j = 0; j < 4; ++j) acc[rg][j] = zf4;
#pragma unroll
  for (int kk = 0; kk < 256; kk += 32) {
    bf16x8 af0 = *(const bf16x8*)&A[c][kk + 8 * g];
    bf16x8 af1 = *(const bf16x8*)&A[16 + c][kk + 8 * g];
#pragma unroll
    for (int j = 0; j < 4; ++j) {
      bf16x8 bfr = asfrag(*(const uint4*)(w1T + (size_t)(n0 + 16 * j + c) * 256 + kk + 8 * g));
      acc[0][j] = __builtin_amdgcn_mfma_f32_16x16x32_bf16(af0, bfr, acc[0][j], 0, 0, 0);
      acc[1][j] = __builtin_amdgcn_mfma_f32_16x16x32_bf16(af1, bfr, acc[1][j], 0, 0, 0);
    }
  }
  __syncthreads();                         // all waves done reading A
#pragma unroll
  for (int j = 0; j < 4; ++j) {
    const int n = n0 + 16 * j + c;
    const float bv = b1[n];
#pragma unroll
    for (int rg = 0; rg < 2; ++rg)
#pragma unroll
      for (int r = 0; r < 4; ++r) {
        float v = acc[rg][j][r] + bv;
        A[16 * rg + 4 * g + r][n] = bfu(v > 0.f ? v : 0.f);
      }
  }
  __syncthreads();

  // ---- GEMM3: h @ W2 ----
#pragma unroll
  for (int rg = 0; rg < 2; ++rg)
#pragma unroll
    for (int j = 0; j < 4; ++j) acc[rg][j] = zf4;
#pragma unroll
  for (int kk = 0; kk < 256; kk += 32) {
    bf16x8 af0 = *(const bf16x8*)&A[c][kk + 8 * g];
    bf16x8 af1 = *(const bf16x8*)&A[16 + c][kk + 8 * g];
#pragma unroll
    for (int j = 0; j < 4; ++j) {
      bf16x8 bfr = asfrag(*(const uint4*)(w2T + (size_t)(n0 + 16 * j + c) * 256 + kk + 8 * g));
      acc[0][j] = __builtin_amdgcn_mfma_f32_16x16x32_bf16(af0, bfr, acc[0][j], 0, 0, 0);
      acc[1][j] = __builtin_amdgcn_mfma_f32_16x16x32_bf16(af1, bfr, acc[1][j], 0, 0, 0);
    }
  }
  // ---- epilogue3: z = acc + b2 + t1 (regs); LN2 -> out ----
  {
    float b2v[4];
#pragma unroll
    for (int j = 0; j < 4; ++j) b2v[j] = b2[n0 + 16 * j + c];
#pragma unroll
    for (int rg = 0; rg < 2; ++rg)
#pragma unroll
      for (int r = 0; r < 4; ++r) {
        const int rl = 16 * rg + 4 * g + r;
        float a1 = 0.f, a2 = 0.f;
#pragma unroll
        for (int j = 0; j < 4; ++j) {
          float z = acc[rg][j][r] + b2v[j] + t1[rg][j][r];
          t1[rg][j][r] = z;
          a1 += z; a2 += z * z;
        }
#pragma unroll
        for (int off = 1; off < 16; off <<= 1) {
          a1 += __shfl_xor(a1, off);
          a2 += __shfl_xor(a2, off);
        }
        if (c == 0) { PS1[rl][w] = a1; PS2[rl][w] = a2; }
      }
  }
  __syncthreads();
#pragma unroll
  for (int rg = 0; rg < 2; ++rg)
#pragma unroll
    for (int r = 0; r < 4; ++r) {
      const int rl = 16 * rg + 4 * g + r;
      float s1 = PS1[rl][0] + PS1[rl][1] + PS1[rl][2] + PS1[rl][3];
      float s2 = PS2[rl][0] + PS2[rl][1] + PS2[rl][2] + PS2[rl][3];
      mean[rg][r] = s1 * (1.f / 256.f);
      inv[rg][r] = rsqrtf(s2 * (1.f / 256.f) - mean[rg][r] * mean[rg][r] + 1e-5f);
    }
#pragma unroll
  for (int j = 0; j < 4; ++j) {
    const int n = n0 + 16 * j + c;
    const float gv = g2[n], bev = be2[n];
#pragma unroll
    for (int rg = 0; rg < 2; ++rg)
#pragma unroll
      for (int r = 0; r < 4; ++r)
        out[(size_t)(m0 + 16 * rg + 4 * g + r) * 256 + n]
            = (t1[rg][j][r] - mean[rg][r]) * inv[rg][r] * gv + bev;
  }
}

extern "C" void kernel_launch(void* const* d_in, const int* in_sizes, int n_in,
                              void* d_out, int out_size, void* d_ws, size_t ws_size,
                              hipStream_t stream) {
  const float* qdt   = (const float*)d_in[0];
  const float* boxes = (const float*)d_in[1];
  const int*   mask  = (const int*)d_in[2];
  const float* Wq = (const float*)d_in[3];
  const float* bq = (const float*)d_in[4];
  const float* Wk = (const float*)d_in[5];
  const float* bk = (const float*)d_in[6];
  const float* Wv = (const float*)d_in[7];
  const float* bv = (const float*)d_in[8];
  const float* Wo = (const float*)d_in[9];
  const float* bo = (const float*)d_in[10];
  const float* W1 = (const float*)d_in[11];
  const float* b1 = (const float*)d_in[12];
  const float* W2 = (const float*)d_in[13];
  const float* b2 = (const float*)d_in[14];
  const float* g1  = (const float*)d_in[15];
  const float* be1 = (const float*)d_in[16];
  const float* g2  = (const float*)d_in[17];
  const float* be2 = (const float*)d_in[18];

  char* ws = (char*)d_ws;
  float* xp    = (float*)(ws + 0);          // [8192,256] f32 permuted residual
  u16*   xb    = (u16*)  (ws + 8388608);
  u16*   qbuf  = (u16*)  (ws + 12582912);   // q, LAMBDA-scaled
  u16*   kbuf  = (u16*)  (ws + 16777216);   // [B][H][2048][32]
  u16*   vtbuf = (u16*)  (ws + 20971520);   // [256][8192]
  u16*   obuf  = (u16*)  (ws + 25165824);
  u16*   wqkvT = (u16*)  (ws + 46137344);   // [768,256]
  u16*   woT   = (u16*)  (ws + 46530560);
  u16*   w1T   = (u16*)  (ws + 46661632);
  u16*   w2T   = (u16*)  (ws + 46792704);
  float* bqkv  = (float*)(ws + 46923776);
  unsigned char* m8 = (unsigned char*)(ws + 46926848);  // [2048,2048] u8

  // merged prep: xp/xb (2048 blk) + mask->m8 (4096 blk) + weights (1539 blk)
  prep_kernel<<<7683, 256, 0, stream>>>(qdt, boxes, mask, Wq, Wk, Wv, Wo, W1, W2,
                                        bq, bk, bv, xp, xb, m8,
                                        wqkvT, woT, w1T, w2T, bqkv);
  // fused Q(scaled)/K(relayout) + V^T: 1024 + 512 blocks
  gemm_qkvt_kernel<<<1536, 256, 0, stream>>>(xb, wqkvT, bqkv, qbuf, kbuf, vtbuf);
  // attention
  attn_kernel<<<1024, 256, 0, stream>>>(qbuf, kbuf, vtbuf, m8, obuf);
  // fused tail: Wo+res -> LN1 -> FF1+relu -> FF2+res -> LN2 -> d_out
  tail_kernel<<<256, 256, 0, stream>>>(obuf, woT, w1T, w2T, xp,
                                       bo, b1, b2, g1, be1, g2, be2, (float*)d_out);
}